// Round 4
// baseline (1859.294 us; speedup 1.0000x reference)
//
#include <hip/hip_runtime.h>

typedef unsigned short u16;
typedef unsigned int u32;
typedef __attribute__((ext_vector_type(8))) short short8;
typedef __attribute__((ext_vector_type(4))) float f32x4;

#define NN 50000
#define EE 800000

__device__ __forceinline__ float bf2f(u16 u){ union{u32 i; float f;} v; v.i=((u32)u)<<16; return v.f; }
__device__ __forceinline__ u16 f2bf(float f){ union{float f; u32 i;} v; v.f=f; u32 b=v.i; b += 0x7FFFu + ((b>>16)&1u); return (u16)(b>>16); }
__device__ __forceinline__ float sigmoidf_(float x){ return 1.0f/(1.0f+__expf(-x)); }

__device__ __forceinline__ void cvt8(uint4 q, float* f){
  f[0]=bf2f((u16)(q.x&0xFFFF)); f[1]=bf2f((u16)(q.x>>16));
  f[2]=bf2f((u16)(q.y&0xFFFF)); f[3]=bf2f((u16)(q.y>>16));
  f[4]=bf2f((u16)(q.z&0xFFFF)); f[5]=bf2f((u16)(q.z>>16));
  f[6]=bf2f((u16)(q.w&0xFFFF)); f[7]=bf2f((u16)(q.w>>16));
}
__device__ __forceinline__ uint4 pack8(const float* f){
  uint4 q;
  q.x=(u32)f2bf(f[0])|((u32)f2bf(f[1])<<16);
  q.y=(u32)f2bf(f[2])|((u32)f2bf(f[3])<<16);
  q.z=(u32)f2bf(f[4])|((u32)f2bf(f[5])<<16);
  q.w=(u32)f2bf(f[6])|((u32)f2bf(f[7])<<16);
  return q;
}

// dtype-polymorphic loads/stores. FP32=0: tensors are bf16 (u16). FP32=1: tensors are float.
template<int FP32> struct IO;
template<> struct IO<0> {
  static __device__ __forceinline__ float ld(const void* p, int i){ return bf2f(((const u16*)p)[i]); }
  static __device__ __forceinline__ void ld8(const void* p, int i, float* f){
    cvt8(*(const uint4*)((const u16*)p + i), f);
  }
  static __device__ __forceinline__ void st(void* p, int i, float v){ ((u16*)p)[i] = f2bf(v); }
};
template<> struct IO<1> {
  static __device__ __forceinline__ float ld(const void* p, int i){ return ((const float*)p)[i]; }
  static __device__ __forceinline__ void ld8(const void* p, int i, float* f){
    f32x4 a = *(const f32x4*)((const float*)p + i);
    f32x4 b = *(const f32x4*)((const float*)p + i + 4);
    f[0]=a[0]; f[1]=a[1]; f[2]=a[2]; f[3]=a[3];
    f[4]=b[0]; f[5]=b[1]; f[6]=b[2]; f[7]=b[3];
  }
  static __device__ __forceinline__ void st(void* p, int i, float v){ ((float*)p)[i] = v; }
};

// bf16-pair atomic add via u32 CAS
__device__ __forceinline__ void atomic_add_bf16pair(u32* addr, float lo, float hi){
  u32 old = *addr, assumed;
  do {
    assumed = old;
    float flo = bf2f((u16)(assumed & 0xFFFFu)) + lo;
    float fhi = bf2f((u16)(assumed >> 16)) + hi;
    u32 newv = (u32)f2bf(flo) | ((u32)f2bf(fhi) << 16);
    if (newv == assumed) return;
    old = atomicCAS(addr, assumed, newv);
  } while (old != assumed);
}

// ---------------- dtype probe ----------------
// bf16 data: even-indexed u16s decode to |v| < 1e3, essentially never exactly 0.
// fp32 data: even-indexed u16s are float low-halves: wild magnitudes (full precision)
//            or exactly 0 (if values are bf16-rounded but stored as fp32).
__global__ void k_probe(const u16* __restrict__ hraw, int* __restrict__ flag){
  if (threadIdx.x==0 && blockIdx.x==0){
    float mx = 0.f; int zc = 0;
    for (int i = 0; i < 256; i += 2){
      u16 u = hraw[i];
      if (u == 0) zc++;
      float v = fabsf(bf2f(u));
      mx = fmaxf(mx, v);
    }
    flag[0] = (mx > 1e3f || zc > 32) ? 1 : 0;
  }
}

// ---------------- weight pack (output always bf16) ----------------
// WprojT [256 n][192 k]: n<128: P13 col n (k<128: We1[k][n]; k in[128,192): We1[265+k-128][n])
//                        n>=128: h_dst-proj col n-128 (k<128: We1[128+k][n-128]; else 0)
template<int FP32>
__global__ __launch_bounds__(256) void k_prep(
    const int* __restrict__ flag,
    const void* __restrict__ We1, const void* __restrict__ We2,
    const void* __restrict__ Wx1, const void* __restrict__ Wh1,
    const void* __restrict__ Wh2,
    u16* __restrict__ WprojT, u16* __restrict__ We2T, u16* __restrict__ Wx1T,
    u16* __restrict__ Wh1T, u16* __restrict__ Wh2T)
{
  if (flag[0] != FP32) return;
  int i = blockIdx.x*256 + threadIdx.x;
  if (i < 49152){
    int n = i/192, k = i%192; float v;
    if (n < 128) v = (k<128) ? IO<FP32>::ld(We1, k*128+n) : IO<FP32>::ld(We1, (265+k-128)*128+n);
    else         v = (k<128) ? IO<FP32>::ld(We1, (128+k)*128+(n-128)) : 0.f;
    WprojT[i] = f2bf(v);
  } else if (i < 65536){
    int j=i-49152; int n=j/128, k=j%128; We2T[j] = f2bf(IO<FP32>::ld(We2, k*128+n));
  } else if (i < 81920){
    int j=i-65536; int n=j/128, k=j%128; Wx1T[j] = f2bf(IO<FP32>::ld(Wx1, k*128+n));
  } else if (i < 114688){
    int j=i-81920; int n=j/256, k=j%256; Wh1T[j] = f2bf(IO<FP32>::ld(Wh1, k*128+n));
  } else if (i < 131072){
    int j=i-114688; int n=j/128, k=j%128; Wh2T[j] = f2bf(IO<FP32>::ld(Wh2, k*128+n));
  }
}

// ---------------- P13 = h@We1[:128] + temb@We1[265:] + b1  (bf16, staged in d_out bytes) ----
template<int FP32>
__global__ __launch_bounds__(256) void k_proj(
    const int* __restrict__ flag,
    const void* __restrict__ h, const void* __restrict__ temb,
    const u16* __restrict__ WprojT, const void* __restrict__ We1b,
    u16* __restrict__ P13)
{
  if (flag[0] != FP32) return;
  __shared__ __align__(16) u16 s_a[64][200];
  int tid = threadIdx.x; int nbase = blockIdx.x*64;
  {
    u32* p = (u32*)&s_a[0][0];
    for (int i = tid; i < 6400; i += 256) p[i] = 0u;
  }
  __syncthreads();
  {
    int r = tid>>2, p = tid&3; int node = nbase + r;
    if (node < NN){
      #pragma unroll
      for (int c=0;c<6;c++){
        int col = p*48 + c*8;
        float f[8];
        if (col<128) IO<FP32>::ld8(h, node*128 + col, f);
        else         IO<FP32>::ld8(temb, node*64 + (col-128), f);
        *(uint4*)&s_a[r][col] = pack8(f);
      }
    }
  }
  __syncthreads();
  int lane=tid&63, wid=tid>>6, quad=lane>>4, l15=lane&15, mb=wid*16;
  f32x4 acc[8];
  #pragma unroll
  for (int nt=0;nt<8;nt++) acc[nt]=(f32x4){0.f,0.f,0.f,0.f};
  #pragma unroll
  for (int ks=0;ks<6;ks++){
    short8 af = *(const short8*)&s_a[mb+l15][ks*32+quad*8];
    #pragma unroll
    for (int nt=0;nt<8;nt++){
      short8 bfr = *(const short8*)(WprojT + (nt*16+l15)*192 + ks*32+quad*8);
      acc[nt] = __builtin_amdgcn_mfma_f32_16x16x32_bf16(af, bfr, acc[nt], 0,0,0);
    }
  }
  #pragma unroll
  for (int r=0;r<4;r++){
    int node = nbase + mb + quad*4 + r;
    if (node < NN){
      #pragma unroll
      for (int nt=0;nt<8;nt++){
        int col = nt*16 + l15;
        P13[node*128+col] = f2bf(acc[nt][r] + IO<FP32>::ld(We1b, col));
      }
    }
  }
}

// ---------------- fused edge kernel: 64 edges/block ----------------
template<int FP32>
__global__ __launch_bounds__(256) void k_edge(
    const int* __restrict__ flag,
    const void* __restrict__ x, const void* __restrict__ ea,
    const void* __restrict__ We1, const void* __restrict__ h,
    const void* __restrict__ We2b, const void* __restrict__ Watt, const void* __restrict__ Wattb,
    const void* __restrict__ Wx1b, const void* __restrict__ Wx2, const void* __restrict__ Wx2b,
    const int* __restrict__ eidx,
    const u16* __restrict__ P13,
    const u16* __restrict__ WprojT,
    const u16* __restrict__ We2T, const u16* __restrict__ Wx1T,
    u16* __restrict__ msgb, float* __restrict__ cagg)
{
  if (flag[0] != FP32) return;
  __shared__ int s_src[64], s_dst[64];
  __shared__ float s_dif[64][4];
  __shared__ __align__(16) u16 s_hid[64][136];
  __shared__ __align__(16) u16 s_m[64][136];
  __shared__ __align__(16) u16 s_hd[64][136];
  int tid = threadIdx.x;
  int ebase = blockIdx.x*64;
  {
    if (tid < 64){ s_src[tid] = eidx[ebase+tid]; s_dst[tid] = eidx[EE+ebase+tid]; }
    u32* p3 = (u32*)&s_dif[0][0];
    p3[tid] = 0u;
  }
  __syncthreads();
  // ---- phase A: pre-activation (P13[src] + dist + edge_attr terms), gather h[dst]
  {
    int el = tid>>2, p = tid&3;
    int srcI = s_src[el], dstI = s_dst[el];
    float d0 = IO<FP32>::ld(x, srcI*3+0) - IO<FP32>::ld(x, dstI*3+0);
    float d1 = IO<FP32>::ld(x, srcI*3+1) - IO<FP32>::ld(x, dstI*3+1);
    float d2 = IO<FP32>::ld(x, srcI*3+2) - IO<FP32>::ld(x, dstI*3+2);
    float dsq = d0*d0 + d1*d1 + d2*d2;
    if (p==0){ s_dif[el][0]=d0; s_dif[el][1]=d1; s_dif[el][2]=d2; }
    float eav[8]; IO<FP32>::ld8(ea, (ebase+el)*8, eav);
    const u16* p13r = P13 + srcI*128;
    #pragma unroll
    for (int c=0;c<4;c++){
      int col = p*32 + c*8;
      float fw[8], pre[8], hd[8];
      cvt8(*(const uint4*)(p13r+col), pre);
      IO<FP32>::ld8(We1, 256*128 + col, fw);
      #pragma unroll
      for (int i2=0;i2<8;i2++) pre[i2] += dsq*fw[i2];
      #pragma unroll
      for (int t=0;t<8;t++){
        IO<FP32>::ld8(We1, (257+t)*128 + col, fw);
        #pragma unroll
        for (int i2=0;i2<8;i2++) pre[i2] += eav[t]*fw[i2];
      }
      *(uint4*)&s_hid[el][col] = pack8(pre);
      IO<FP32>::ld8(h, dstI*128 + col, hd);
      *(uint4*)&s_hd[el][col] = pack8(hd);
    }
  }
  __syncthreads();
  int lane=tid&63, wid=tid>>6, quad=lane>>4, l15=lane&15, mb=wid*16;
  // ---- GEMM-G: h_dst @ We1[128:256] (B = WprojT rows 128..255), fold + silu
  {
    f32x4 accg[8];
    #pragma unroll
    for (int nt=0;nt<8;nt++) accg[nt]=(f32x4){0.f,0.f,0.f,0.f};
    #pragma unroll
    for (int ks=0;ks<4;ks++){
      short8 af = *(const short8*)&s_hd[mb+l15][ks*32+quad*8];
      #pragma unroll
      for (int nt=0;nt<8;nt++){
        short8 bfr = *(const short8*)(WprojT + (128 + nt*16+l15)*192 + ks*32+quad*8);
        accg[nt] = __builtin_amdgcn_mfma_f32_16x16x32_bf16(af, bfr, accg[nt], 0,0,0);
      }
    }
    #pragma unroll
    for (int r=0;r<4;r++){
      int row = mb + quad*4 + r;
      #pragma unroll
      for (int nt=0;nt<8;nt++){
        int col = nt*16+l15;
        float u = bf2f(s_hid[row][col]) + accg[nt][r];
        u = u*sigmoidf_(u);
        s_hid[row][col] = f2bf(u);
      }
    }
  }
  __syncthreads();
  // ---- GEMM1: m_pre = hid @ We2
  f32x4 acc[8];
  #pragma unroll
  for (int nt=0;nt<8;nt++) acc[nt]=(f32x4){0.f,0.f,0.f,0.f};
  #pragma unroll
  for (int ks=0;ks<4;ks++){
    short8 af = *(const short8*)&s_hid[mb+l15][ks*32+quad*8];
    #pragma unroll
    for (int nt=0;nt<8;nt++){
      short8 bfr = *(const short8*)(We2T + (nt*16+l15)*128 + ks*32+quad*8);
      acc[nt] = __builtin_amdgcn_mfma_f32_16x16x32_bf16(af, bfr, acc[nt], 0,0,0);
    }
  }
  // ---- epilogue: attention gate; write s_m + CAS-atomic msg_agg (bf16 pairs)
  float b2v[8], wav[8];
  #pragma unroll
  for (int nt=0;nt<8;nt++){ b2v[nt]=IO<FP32>::ld(We2b, nt*16+l15); wav[nt]=IO<FP32>::ld(Watt, nt*16+l15); }
  float attb = IO<FP32>::ld(Wattb, 0);
  float mval[8][4]; float dotr[4];
  #pragma unroll
  for (int r=0;r<4;r++){
    float s=0.f;
    #pragma unroll
    for (int nt=0;nt<8;nt++){ mval[nt][r]=acc[nt][r]+b2v[nt]; s += mval[nt][r]*wav[nt]; }
    dotr[r]=s;
  }
  #pragma unroll
  for (int off=1;off<16;off<<=1){
    #pragma unroll
    for (int r=0;r<4;r++) dotr[r] += __shfl_xor(dotr[r], off);
  }
  #pragma unroll
  for (int r=0;r<4;r++){
    float att = sigmoidf_(dotr[r]+attb);
    int erow = mb + quad*4 + r;
    int dstN = s_dst[erow];
    #pragma unroll
    for (int nt=0;nt<8;nt++){
      float v = mval[nt][r]*att;
      mval[nt][r] = v;
      s_m[erow][nt*16+l15] = f2bf(v);
    }
    #pragma unroll
    for (int nt=0;nt<8;nt++){
      float part = __shfl_xor(mval[nt][r], 1);
      if ((l15 & 1) == 0){
        atomic_add_bf16pair((u32*)(msgb + dstN*128 + nt*16 + l15), mval[nt][r], part);
      }
    }
  }
  __syncthreads();
  // ---- GEMM2: ch_pre = m @ Wx1
  f32x4 acc2[8];
  #pragma unroll
  for (int nt=0;nt<8;nt++) acc2[nt]=(f32x4){0.f,0.f,0.f,0.f};
  #pragma unroll
  for (int ks=0;ks<4;ks++){
    short8 af = *(const short8*)&s_m[mb+l15][ks*32+quad*8];
    #pragma unroll
    for (int nt=0;nt<8;nt++){
      short8 bfr = *(const short8*)(Wx1T + (nt*16+l15)*128 + ks*32+quad*8);
      acc2[nt] = __builtin_amdgcn_mfma_f32_16x16x32_bf16(af, bfr, acc2[nt], 0,0,0);
    }
  }
  // ---- epilogue: coord weight + fp32 atomics
  float bx1v[8], wx2v[8];
  #pragma unroll
  for (int nt=0;nt<8;nt++){ bx1v[nt]=IO<FP32>::ld(Wx1b, nt*16+l15); wx2v[nt]=IO<FP32>::ld(Wx2, nt*16+l15); }
  float bx2f = IO<FP32>::ld(Wx2b, 0);
  float dc[4];
  #pragma unroll
  for (int r=0;r<4;r++){
    float s=0.f;
    #pragma unroll
    for (int nt=0;nt<8;nt++){
      float u = acc2[nt][r] + bx1v[nt];
      u = u*sigmoidf_(u);
      s += u*wx2v[nt];
    }
    dc[r]=s;
  }
  #pragma unroll
  for (int off=1;off<16;off<<=1){
    #pragma unroll
    for (int r=0;r<4;r++) dc[r] += __shfl_xor(dc[r], off);
  }
  #pragma unroll
  for (int r=0;r<4;r++){
    float cw = tanhf(dc[r]+bx2f);
    if (l15==0){
      int erow = mb + quad*4 + r;
      int dstN = s_dst[erow];
      atomicAdd(&cagg[dstN*4+0], s_dif[erow][0]*cw);
      atomicAdd(&cagg[dstN*4+1], s_dif[erow][1]*cw);
      atomicAdd(&cagg[dstN*4+2], s_dif[erow][2]*cw);
      atomicAdd(&cagg[dstN*4+3], 1.0f);
    }
  }
}

// ---------------- node update ----------------
template<int FP32>
__global__ __launch_bounds__(256) void k_node(
    const int* __restrict__ flag,
    const void* __restrict__ h, const void* __restrict__ x,
    const u16* __restrict__ msgb, const float* __restrict__ cagg,
    const u16* __restrict__ Wh1T, const void* __restrict__ Wh1b,
    const u16* __restrict__ Wh2T, const void* __restrict__ Wh2b,
    void* __restrict__ out)
{
  if (flag[0] != FP32) return;
  __shared__ __align__(16) u16 s_a[64][264];
  __shared__ __align__(16) u16 s_u[64][136];
  int tid = threadIdx.x; int nbase = blockIdx.x*64;
  {
    u32* p1 = (u32*)&s_a[0][0];
    for (int i = tid; i < 8448; i += 256) p1[i] = 0u;
  }
  __syncthreads();
  {
    int r = tid>>2, p = tid&3; int node = nbase + r;
    if (node < NN){
      #pragma unroll
      for (int c=0;c<8;c++){
        int col = p*64 + c*8;
        if (col < 128){
          float f[8]; IO<FP32>::ld8(h, node*128 + col, f);
          *(uint4*)&s_a[r][col] = pack8(f);
        } else {
          *(uint4*)&s_a[r][col] = *(const uint4*)(msgb + node*128 + (col-128));
        }
      }
    }
  }
  __syncthreads();
  int lane=tid&63, wid=tid>>6, quad=lane>>4, l15=lane&15, mb=wid*16;
  f32x4 acc[8];
  #pragma unroll
  for (int nt=0;nt<8;nt++) acc[nt]=(f32x4){0.f,0.f,0.f,0.f};
  #pragma unroll
  for (int ks=0;ks<8;ks++){
    short8 af = *(const short8*)&s_a[mb+l15][ks*32+quad*8];
    #pragma unroll
    for (int nt=0;nt<8;nt++){
      short8 bfr = *(const short8*)(Wh1T + (nt*16+l15)*256 + ks*32+quad*8);
      acc[nt] = __builtin_amdgcn_mfma_f32_16x16x32_bf16(af, bfr, acc[nt], 0,0,0);
    }
  }
  #pragma unroll
  for (int r=0;r<4;r++){
    int row = mb + quad*4 + r;
    #pragma unroll
    for (int nt=0;nt<8;nt++){
      int col = nt*16+l15;
      float u = acc[nt][r] + IO<FP32>::ld(Wh1b, col);
      u = u*sigmoidf_(u);
      s_u[row][col] = f2bf(u);
    }
  }
  __syncthreads();
  f32x4 acc2[8];
  #pragma unroll
  for (int nt=0;nt<8;nt++) acc2[nt]=(f32x4){0.f,0.f,0.f,0.f};
  #pragma unroll
  for (int ks=0;ks<4;ks++){
    short8 af = *(const short8*)&s_u[mb+l15][ks*32+quad*8];
    #pragma unroll
    for (int nt=0;nt<8;nt++){
      short8 bfr = *(const short8*)(Wh2T + (nt*16+l15)*128 + ks*32+quad*8);
      acc2[nt] = __builtin_amdgcn_mfma_f32_16x16x32_bf16(af, bfr, acc2[nt], 0,0,0);
    }
  }
  #pragma unroll
  for (int r=0;r<4;r++){
    int node = nbase + mb + quad*4 + r;
    if (node < NN){
      #pragma unroll
      for (int nt=0;nt<8;nt++){
        int col = nt*16+l15;
        float v = IO<FP32>::ld(h, node*128+col) + acc2[nt][r] + IO<FP32>::ld(Wh2b, col);
        IO<FP32>::st(out, node*128+col, v);
      }
    }
  }
  if (tid < 64){
    int node = nbase + tid;
    if (node < NN){
      float inv = 1.0f/(cagg[node*4+3] + 1.0f);
      #pragma unroll
      for (int c=0;c<3;c++){
        float v = IO<FP32>::ld(x, node*3+c) + cagg[node*4+c]*inv;
        IO<FP32>::st(out, NN*128 + node*3 + c, v);
      }
    }
  }
}

extern "C" void kernel_launch(void* const* d_in, const int* in_sizes, int n_in,
                              void* d_out, int out_size, void* d_ws, size_t ws_size,
                              hipStream_t stream) {
  const void* h     = d_in[0];
  const void* x     = d_in[1];
  const void* ea    = d_in[2];
  const void* temb  = d_in[3];
  const void* We1   = d_in[4];
  const void* We1b  = d_in[5];
  const void* We2   = d_in[6];
  const void* We2b  = d_in[7];
  const void* Watt  = d_in[8];
  const void* Wattb = d_in[9];
  const void* Wx1   = d_in[10];
  const void* Wx1b  = d_in[11];
  const void* Wx2   = d_in[12];
  const void* Wx2b  = d_in[13];
  const void* Wh1   = d_in[14];
  const void* Wh1b  = d_in[15];
  const void* Wh2   = d_in[16];
  const void* Wh2b  = d_in[17];
  const int* eidx   = (const int*)d_in[18];
  char* ws = (char*)d_ws;

  // ws layout (13,862,400 bytes total):
  u16* WprojT = (u16*)(ws + 0);          //  98,304
  u16* We2T   = (u16*)(ws + 98304);      //  32,768
  u16* Wx1T   = (u16*)(ws + 131072);     //  32,768
  u16* Wh1T   = (u16*)(ws + 163840);     //  65,536
  u16* Wh2T   = (u16*)(ws + 229376);     //  32,768  -> 262,144
  float* cagg = (float*)(ws + 262144);   // 800,000  -> 1,062,144
  int* flag   = (int*)(ws + 1062144);    //     256  -> 1,062,400
  u16* msgb   = (u16*)(ws + 1062400);    // 12,800,000 -> 13,862,400
  u16* P13    = (u16*)d_out;             // 12.8 MB staged in d_out bytes (overwritten by k_node)

  hipMemsetAsync(ws + 262144, 0, 13600256, stream);
  k_probe<<<1, 64, 0, stream>>>((const u16*)h, flag);
  k_prep<0><<<512, 256, 0, stream>>>(flag, We1, We2, Wx1, Wh1, Wh2, WprojT, We2T, Wx1T, Wh1T, Wh2T);
  k_prep<1><<<512, 256, 0, stream>>>(flag, We1, We2, Wx1, Wh1, Wh2, WprojT, We2T, Wx1T, Wh1T, Wh2T);
  k_proj<0><<<(NN+63)/64, 256, 0, stream>>>(flag, h, temb, WprojT, We1b, P13);
  k_proj<1><<<(NN+63)/64, 256, 0, stream>>>(flag, h, temb, WprojT, We1b, P13);
  k_edge<0><<<EE/64, 256, 0, stream>>>(flag, x, ea, We1, h, We2b, Watt, Wattb, Wx1b, Wx2, Wx2b,
                                       eidx, P13, WprojT, We2T, Wx1T, msgb, cagg);
  k_edge<1><<<EE/64, 256, 0, stream>>>(flag, x, ea, We1, h, We2b, Watt, Wattb, Wx1b, Wx2, Wx2b,
                                       eidx, P13, WprojT, We2T, Wx1T, msgb, cagg);
  k_node<0><<<(NN+63)/64, 256, 0, stream>>>(flag, h, x, msgb, cagg, Wh1T, Wh1b, Wh2T, Wh2b, d_out);
  k_node<1><<<(NN+63)/64, 256, 0, stream>>>(flag, h, x, msgb, cagg, Wh1T, Wh1b, Wh2T, Wh2b, d_out);
}

// Round 5
// 1115.304 us; speedup vs baseline: 1.6671x; 1.6671x over previous
//
#include <hip/hip_runtime.h>

typedef unsigned short u16;
typedef unsigned int u32;
typedef __attribute__((ext_vector_type(8))) short short8;
typedef __attribute__((ext_vector_type(4))) float f32x4;

#define NN 50000
#define EE 800000

__device__ __forceinline__ float bf2f(u16 u){ union{u32 i; float f;} v; v.i=((u32)u)<<16; return v.f; }
__device__ __forceinline__ u16 f2bf(float f){ union{float f; u32 i;} v; v.f=f; u32 b=v.i; b += 0x7FFFu + ((b>>16)&1u); return (u16)(b>>16); }
__device__ __forceinline__ float sigmoidf_(float x){ return 1.0f/(1.0f+__expf(-x)); }

__device__ __forceinline__ void cvt8(uint4 q, float* f){
  f[0]=bf2f((u16)(q.x&0xFFFF)); f[1]=bf2f((u16)(q.x>>16));
  f[2]=bf2f((u16)(q.y&0xFFFF)); f[3]=bf2f((u16)(q.y>>16));
  f[4]=bf2f((u16)(q.z&0xFFFF)); f[5]=bf2f((u16)(q.z>>16));
  f[6]=bf2f((u16)(q.w&0xFFFF)); f[7]=bf2f((u16)(q.w>>16));
}
__device__ __forceinline__ uint4 pack8(const float* f){
  uint4 q;
  q.x=(u32)f2bf(f[0])|((u32)f2bf(f[1])<<16);
  q.y=(u32)f2bf(f[2])|((u32)f2bf(f[3])<<16);
  q.z=(u32)f2bf(f[4])|((u32)f2bf(f[5])<<16);
  q.w=(u32)f2bf(f[6])|((u32)f2bf(f[7])<<16);
  return q;
}

// dtype-polymorphic loads/stores. FP32=0: tensors bf16. FP32=1: tensors fp32.
template<int FP32> struct IO;
template<> struct IO<0> {
  static __device__ __forceinline__ float ld(const void* p, int i){ return bf2f(((const u16*)p)[i]); }
  static __device__ __forceinline__ void ld8(const void* p, int i, float* f){
    cvt8(*(const uint4*)((const u16*)p + i), f);
  }
  static __device__ __forceinline__ void st(void* p, int i, float v){ ((u16*)p)[i] = f2bf(v); }
};
template<> struct IO<1> {
  static __device__ __forceinline__ float ld(const void* p, int i){ return ((const float*)p)[i]; }
  static __device__ __forceinline__ void ld8(const void* p, int i, float* f){
    f32x4 a = *(const f32x4*)((const float*)p + i);
    f32x4 b = *(const f32x4*)((const float*)p + i + 4);
    f[0]=a[0]; f[1]=a[1]; f[2]=a[2]; f[3]=a[3];
    f[4]=b[0]; f[5]=b[1]; f[6]=b[2]; f[7]=b[3];
  }
  static __device__ __forceinline__ void st(void* p, int i, float v){ ((float*)p)[i] = v; }
};

// bf16-pair atomic add via u32 CAS (fallback tier only)
__device__ __forceinline__ void atomic_add_bf16pair(u32* addr, float lo, float hi){
  u32 old = *addr, assumed;
  do {
    assumed = old;
    float flo = bf2f((u16)(assumed & 0xFFFFu)) + lo;
    float fhi = bf2f((u16)(assumed >> 16)) + hi;
    u32 newv = (u32)f2bf(flo) | ((u32)f2bf(fhi) << 16);
    if (newv == assumed) return;
    old = atomicCAS(addr, assumed, newv);
  } while (old != assumed);
}

// ---------------- dtype probe (proven R4) ----------------
__global__ void k_probe(const u16* __restrict__ hraw, int* __restrict__ flag){
  if (threadIdx.x==0 && blockIdx.x==0){
    float mx = 0.f; int zc = 0;
    for (int i = 0; i < 256; i += 2){
      u16 u = hraw[i];
      if (u == 0) zc++;
      float v = fabsf(bf2f(u));
      mx = fmaxf(mx, v);
    }
    flag[0] = (mx > 1e3f || zc > 32) ? 1 : 0;
  }
}

// ---------------- weight pack (output always bf16) ----------------
// WprojT [256 n][192 k]: n<128: P13 col n (k<128: We1[k][n]; k in[128,192): We1[265+k-128][n])
//                        n>=128: P2 col n-128 (k<128: We1[128+k][n-128]; else 0)
template<int FP32>
__global__ __launch_bounds__(256) void k_prep(
    const int* __restrict__ flag,
    const void* __restrict__ We1, const void* __restrict__ We2,
    const void* __restrict__ Wx1, const void* __restrict__ Wh1,
    const void* __restrict__ Wh2,
    u16* __restrict__ WprojT, u16* __restrict__ We2T, u16* __restrict__ Wx1T,
    u16* __restrict__ Wh1T, u16* __restrict__ Wh2T)
{
  if (flag[0] != FP32) return;
  int i = blockIdx.x*256 + threadIdx.x;
  if (i < 49152){
    int n = i/192, k = i%192; float v;
    if (n < 128) v = (k<128) ? IO<FP32>::ld(We1, k*128+n) : IO<FP32>::ld(We1, (265+k-128)*128+n);
    else         v = (k<128) ? IO<FP32>::ld(We1, (128+k)*128+(n-128)) : 0.f;
    WprojT[i] = f2bf(v);
  } else if (i < 65536){
    int j=i-49152; int n=j/128, k=j%128; We2T[j] = f2bf(IO<FP32>::ld(We2, k*128+n));
  } else if (i < 81920){
    int j=i-65536; int n=j/128, k=j%128; Wx1T[j] = f2bf(IO<FP32>::ld(Wx1, k*128+n));
  } else if (i < 114688){
    int j=i-81920; int n=j/256, k=j%256; Wh1T[j] = f2bf(IO<FP32>::ld(Wh1, k*128+n));
  } else if (i < 131072){
    int j=i-114688; int n=j/128, k=j%128; Wh2T[j] = f2bf(IO<FP32>::ld(Wh2, k*128+n));
  }
}

// ---------------- P13 (= h@We1[:128]+temb@We1[265:]+b1) and optionally P2 (= h@We1[128:256]) ----
template<int FP32, int WP2>
__global__ __launch_bounds__(256) void k_proj(
    const int* __restrict__ flag,
    const void* __restrict__ h, const void* __restrict__ temb,
    const u16* __restrict__ WprojT, const void* __restrict__ We1b,
    u16* __restrict__ P13, u16* __restrict__ P2)
{
  if (flag[0] != FP32) return;
  constexpr int NT = WP2 ? 16 : 8;
  __shared__ __align__(16) u16 s_a[64][200];
  int tid = threadIdx.x; int nbase = blockIdx.x*64;
  {
    u32* p = (u32*)&s_a[0][0];
    for (int i = tid; i < 6400; i += 256) p[i] = 0u;
  }
  __syncthreads();
  {
    int r = tid>>2, p = tid&3; int node = nbase + r;
    if (node < NN){
      #pragma unroll
      for (int c=0;c<6;c++){
        int col = p*48 + c*8;
        float f[8];
        if (col<128) IO<FP32>::ld8(h, node*128 + col, f);
        else         IO<FP32>::ld8(temb, node*64 + (col-128), f);
        *(uint4*)&s_a[r][col] = pack8(f);
      }
    }
  }
  __syncthreads();
  int lane=tid&63, wid=tid>>6, quad=lane>>4, l15=lane&15, mb=wid*16;
  f32x4 acc[NT];
  #pragma unroll
  for (int nt=0;nt<NT;nt++) acc[nt]=(f32x4){0.f,0.f,0.f,0.f};
  #pragma unroll
  for (int ks=0;ks<6;ks++){
    short8 af = *(const short8*)&s_a[mb+l15][ks*32+quad*8];
    #pragma unroll
    for (int nt=0;nt<NT;nt++){
      short8 bfr = *(const short8*)(WprojT + (nt*16+l15)*192 + ks*32+quad*8);
      acc[nt] = __builtin_amdgcn_mfma_f32_16x16x32_bf16(af, bfr, acc[nt], 0,0,0);
    }
  }
  #pragma unroll
  for (int r=0;r<4;r++){
    int node = nbase + mb + quad*4 + r;
    if (node < NN){
      #pragma unroll
      for (int nt=0;nt<NT;nt++){
        int colg = nt*16 + l15;
        float v = acc[nt][r];
        if (colg < 128) P13[node*128+colg] = f2bf(v + IO<FP32>::ld(We1b, colg));
        else if (WP2)   P2[node*128+(colg-128)] = f2bf(v);
      }
    }
  }
}

// ---------------- fused edge kernel: 64 edges/block ----------------
// TIERA=1: P2 precomputed (read P2[dst], no GEMM-G), msg via native fp32 atomicAdd into msgf.
// TIERA=0: R4-proven path: gather h[dst], GEMM-G in-kernel, msg via bf16-pair CAS into msgb.
template<int FP32, int TIERA>
__global__ __launch_bounds__(256) void k_edge(
    const int* __restrict__ flag,
    const void* __restrict__ x, const void* __restrict__ ea,
    const void* __restrict__ We1, const void* __restrict__ h,
    const void* __restrict__ We2b, const void* __restrict__ Watt, const void* __restrict__ Wattb,
    const void* __restrict__ Wx1b, const void* __restrict__ Wx2, const void* __restrict__ Wx2b,
    const int* __restrict__ eidx,
    const u16* __restrict__ P13, const u16* __restrict__ P2,
    const u16* __restrict__ WprojT,
    const u16* __restrict__ We2T, const u16* __restrict__ Wx1T,
    float* __restrict__ msgf, u16* __restrict__ msgb, float* __restrict__ cagg)
{
  if (flag[0] != FP32) return;
  __shared__ int s_src[64], s_dst[64];
  __shared__ float s_dif[64][4];
  __shared__ __align__(16) u16 s_hid[64][136];
  __shared__ __align__(16) u16 s_m[64][136];
  __shared__ __align__(16) u16 s_hd[TIERA?1:64][136];
  int tid = threadIdx.x;
  int ebase = blockIdx.x*64;
  {
    if (tid < 64){ s_src[tid] = eidx[ebase+tid]; s_dst[tid] = eidx[EE+ebase+tid]; }
    u32* p3 = (u32*)&s_dif[0][0];
    p3[tid] = 0u;
  }
  __syncthreads();
  // ---- phase A: pre-activation = P13[src] + dist + edge_attr terms (+ P2[dst] if TIERA)
  {
    int el = tid>>2, p = tid&3;
    int srcI = s_src[el], dstI = s_dst[el];
    float d0 = IO<FP32>::ld(x, srcI*3+0) - IO<FP32>::ld(x, dstI*3+0);
    float d1 = IO<FP32>::ld(x, srcI*3+1) - IO<FP32>::ld(x, dstI*3+1);
    float d2 = IO<FP32>::ld(x, srcI*3+2) - IO<FP32>::ld(x, dstI*3+2);
    float dsq = d0*d0 + d1*d1 + d2*d2;
    if (p==0){ s_dif[el][0]=d0; s_dif[el][1]=d1; s_dif[el][2]=d2; }
    float eav[8]; IO<FP32>::ld8(ea, (ebase+el)*8, eav);
    const u16* p13r = P13 + srcI*128;
    #pragma unroll
    for (int c=0;c<4;c++){
      int col = p*32 + c*8;
      float fw[8], pre[8];
      cvt8(*(const uint4*)(p13r+col), pre);
      IO<FP32>::ld8(We1, 256*128 + col, fw);
      #pragma unroll
      for (int i2=0;i2<8;i2++) pre[i2] += dsq*fw[i2];
      #pragma unroll
      for (int t=0;t<8;t++){
        IO<FP32>::ld8(We1, (257+t)*128 + col, fw);
        #pragma unroll
        for (int i2=0;i2<8;i2++) pre[i2] += eav[t]*fw[i2];
      }
      if constexpr (TIERA){
        float fb[8]; cvt8(*(const uint4*)(P2 + dstI*128 + col), fb);
        #pragma unroll
        for (int i2=0;i2<8;i2++){ float u = pre[i2]+fb[i2]; pre[i2] = u*sigmoidf_(u); }
      }
      *(uint4*)&s_hid[el][col] = pack8(pre);
      if constexpr (!TIERA){
        float hd[8]; IO<FP32>::ld8(h, dstI*128 + col, hd);
        *(uint4*)&s_hd[el][col] = pack8(hd);
      }
    }
  }
  __syncthreads();
  int lane=tid&63, wid=tid>>6, quad=lane>>4, l15=lane&15, mb=wid*16;
  if constexpr (!TIERA){
    // ---- GEMM-G: h_dst @ We1[128:256] (B = WprojT rows 128..255), fold + silu
    f32x4 accg[8];
    #pragma unroll
    for (int nt=0;nt<8;nt++) accg[nt]=(f32x4){0.f,0.f,0.f,0.f};
    #pragma unroll
    for (int ks=0;ks<4;ks++){
      short8 af = *(const short8*)&s_hd[mb+l15][ks*32+quad*8];
      #pragma unroll
      for (int nt=0;nt<8;nt++){
        short8 bfr = *(const short8*)(WprojT + (128 + nt*16+l15)*192 + ks*32+quad*8);
        accg[nt] = __builtin_amdgcn_mfma_f32_16x16x32_bf16(af, bfr, accg[nt], 0,0,0);
      }
    }
    #pragma unroll
    for (int r=0;r<4;r++){
      int row = mb + quad*4 + r;
      #pragma unroll
      for (int nt=0;nt<8;nt++){
        int col = nt*16+l15;
        float u = bf2f(s_hid[row][col]) + accg[nt][r];
        u = u*sigmoidf_(u);
        s_hid[row][col] = f2bf(u);
      }
    }
    __syncthreads();
  }
  // ---- GEMM1: m_pre = hid @ We2
  f32x4 acc[8];
  #pragma unroll
  for (int nt=0;nt<8;nt++) acc[nt]=(f32x4){0.f,0.f,0.f,0.f};
  #pragma unroll
  for (int ks=0;ks<4;ks++){
    short8 af = *(const short8*)&s_hid[mb+l15][ks*32+quad*8];
    #pragma unroll
    for (int nt=0;nt<8;nt++){
      short8 bfr = *(const short8*)(We2T + (nt*16+l15)*128 + ks*32+quad*8);
      acc[nt] = __builtin_amdgcn_mfma_f32_16x16x32_bf16(af, bfr, acc[nt], 0,0,0);
    }
  }
  // ---- epilogue: attention gate; write s_m + atomic msg_agg
  float b2v[8], wav[8];
  #pragma unroll
  for (int nt=0;nt<8;nt++){ b2v[nt]=IO<FP32>::ld(We2b, nt*16+l15); wav[nt]=IO<FP32>::ld(Watt, nt*16+l15); }
  float attb = IO<FP32>::ld(Wattb, 0);
  float mval[8][4]; float dotr[4];
  #pragma unroll
  for (int r=0;r<4;r++){
    float s=0.f;
    #pragma unroll
    for (int nt=0;nt<8;nt++){ mval[nt][r]=acc[nt][r]+b2v[nt]; s += mval[nt][r]*wav[nt]; }
    dotr[r]=s;
  }
  #pragma unroll
  for (int off=1;off<16;off<<=1){
    #pragma unroll
    for (int r=0;r<4;r++) dotr[r] += __shfl_xor(dotr[r], off);
  }
  #pragma unroll
  for (int r=0;r<4;r++){
    float att = sigmoidf_(dotr[r]+attb);
    int erow = mb + quad*4 + r;
    int dstN = s_dst[erow];
    #pragma unroll
    for (int nt=0;nt<8;nt++){
      float v = mval[nt][r]*att;
      mval[nt][r] = v;
      s_m[erow][nt*16+l15] = f2bf(v);
      if constexpr (TIERA){
        atomicAdd(msgf + dstN*128 + nt*16 + l15, v);
      }
    }
    if constexpr (!TIERA){
      #pragma unroll
      for (int nt=0;nt<8;nt++){
        float part = __shfl_xor(mval[nt][r], 1);
        if ((l15 & 1) == 0){
          atomic_add_bf16pair((u32*)(msgb + dstN*128 + nt*16 + l15), mval[nt][r], part);
        }
      }
    }
  }
  __syncthreads();
  // ---- GEMM2: ch_pre = m @ Wx1
  f32x4 acc2[8];
  #pragma unroll
  for (int nt=0;nt<8;nt++) acc2[nt]=(f32x4){0.f,0.f,0.f,0.f};
  #pragma unroll
  for (int ks=0;ks<4;ks++){
    short8 af = *(const short8*)&s_m[mb+l15][ks*32+quad*8];
    #pragma unroll
    for (int nt=0;nt<8;nt++){
      short8 bfr = *(const short8*)(Wx1T + (nt*16+l15)*128 + ks*32+quad*8);
      acc2[nt] = __builtin_amdgcn_mfma_f32_16x16x32_bf16(af, bfr, acc2[nt], 0,0,0);
    }
  }
  // ---- epilogue: coord weight + fp32 atomics
  float bx1v[8], wx2v[8];
  #pragma unroll
  for (int nt=0;nt<8;nt++){ bx1v[nt]=IO<FP32>::ld(Wx1b, nt*16+l15); wx2v[nt]=IO<FP32>::ld(Wx2, nt*16+l15); }
  float bx2f = IO<FP32>::ld(Wx2b, 0);
  float dc[4];
  #pragma unroll
  for (int r=0;r<4;r++){
    float s=0.f;
    #pragma unroll
    for (int nt=0;nt<8;nt++){
      float u = acc2[nt][r] + bx1v[nt];
      u = u*sigmoidf_(u);
      s += u*wx2v[nt];
    }
    dc[r]=s;
  }
  #pragma unroll
  for (int off=1;off<16;off<<=1){
    #pragma unroll
    for (int r=0;r<4;r++) dc[r] += __shfl_xor(dc[r], off);
  }
  #pragma unroll
  for (int r=0;r<4;r++){
    float cw = tanhf(dc[r]+bx2f);
    if (l15==0){
      int erow = mb + quad*4 + r;
      int dstN = s_dst[erow];
      atomicAdd(&cagg[dstN*4+0], s_dif[erow][0]*cw);
      atomicAdd(&cagg[dstN*4+1], s_dif[erow][1]*cw);
      atomicAdd(&cagg[dstN*4+2], s_dif[erow][2]*cw);
      atomicAdd(&cagg[dstN*4+3], 1.0f);
    }
  }
}

// ---------------- node update ----------------
template<int FP32, int MSGF>
__global__ __launch_bounds__(256) void k_node(
    const int* __restrict__ flag,
    const void* __restrict__ h, const void* __restrict__ x,
    const float* __restrict__ msgf, const u16* __restrict__ msgb,
    const float* __restrict__ cagg,
    const u16* __restrict__ Wh1T, const void* __restrict__ Wh1b,
    const u16* __restrict__ Wh2T, const void* __restrict__ Wh2b,
    void* __restrict__ out)
{
  if (flag[0] != FP32) return;
  __shared__ __align__(16) u16 s_a[64][264];
  __shared__ __align__(16) u16 s_u[64][136];
  int tid = threadIdx.x; int nbase = blockIdx.x*64;
  {
    u32* p1 = (u32*)&s_a[0][0];
    for (int i = tid; i < 8448; i += 256) p1[i] = 0u;
  }
  __syncthreads();
  {
    int r = tid>>2, p = tid&3; int node = nbase + r;
    if (node < NN){
      #pragma unroll
      for (int c=0;c<8;c++){
        int col = p*64 + c*8;
        if (col < 128){
          float f[8]; IO<FP32>::ld8(h, node*128 + col, f);
          *(uint4*)&s_a[r][col] = pack8(f);
        } else if (MSGF){
          const float* mp = msgf + node*128 + (col-128);
          float f[8];
          *(f32x4*)&f[0] = *(const f32x4*)mp;
          *(f32x4*)&f[4] = *(const f32x4*)(mp+4);
          *(uint4*)&s_a[r][col] = pack8(f);
        } else {
          *(uint4*)&s_a[r][col] = *(const uint4*)(msgb + node*128 + (col-128));
        }
      }
    }
  }
  __syncthreads();
  int lane=tid&63, wid=tid>>6, quad=lane>>4, l15=lane&15, mb=wid*16;
  f32x4 acc[8];
  #pragma unroll
  for (int nt=0;nt<8;nt++) acc[nt]=(f32x4){0.f,0.f,0.f,0.f};
  #pragma unroll
  for (int ks=0;ks<8;ks++){
    short8 af = *(const short8*)&s_a[mb+l15][ks*32+quad*8];
    #pragma unroll
    for (int nt=0;nt<8;nt++){
      short8 bfr = *(const short8*)(Wh1T + (nt*16+l15)*256 + ks*32+quad*8);
      acc[nt] = __builtin_amdgcn_mfma_f32_16x16x32_bf16(af, bfr, acc[nt], 0,0,0);
    }
  }
  #pragma unroll
  for (int r=0;r<4;r++){
    int row = mb + quad*4 + r;
    #pragma unroll
    for (int nt=0;nt<8;nt++){
      int col = nt*16+l15;
      float u = acc[nt][r] + IO<FP32>::ld(Wh1b, col);
      u = u*sigmoidf_(u);
      s_u[row][col] = f2bf(u);
    }
  }
  __syncthreads();
  f32x4 acc2[8];
  #pragma unroll
  for (int nt=0;nt<8;nt++) acc2[nt]=(f32x4){0.f,0.f,0.f,0.f};
  #pragma unroll
  for (int ks=0;ks<4;ks++){
    short8 af = *(const short8*)&s_u[mb+l15][ks*32+quad*8];
    #pragma unroll
    for (int nt=0;nt<8;nt++){
      short8 bfr = *(const short8*)(Wh2T + (nt*16+l15)*128 + ks*32+quad*8);
      acc2[nt] = __builtin_amdgcn_mfma_f32_16x16x32_bf16(af, bfr, acc2[nt], 0,0,0);
    }
  }
  #pragma unroll
  for (int r=0;r<4;r++){
    int node = nbase + mb + quad*4 + r;
    if (node < NN){
      #pragma unroll
      for (int nt=0;nt<8;nt++){
        int col = nt*16+l15;
        float v = IO<FP32>::ld(h, node*128+col) + acc2[nt][r] + IO<FP32>::ld(Wh2b, col);
        IO<FP32>::st(out, node*128+col, v);
      }
    }
  }
  if (tid < 64){
    int node = nbase + tid;
    if (node < NN){
      float inv = 1.0f/(cagg[node*4+3] + 1.0f);
      #pragma unroll
      for (int c=0;c<3;c++){
        float v = IO<FP32>::ld(x, node*3+c) + cagg[node*4+c]*inv;
        IO<FP32>::st(out, NN*128 + node*3 + c, v);
      }
    }
  }
}

extern "C" void kernel_launch(void* const* d_in, const int* in_sizes, int n_in,
                              void* d_out, int out_size, void* d_ws, size_t ws_size,
                              hipStream_t stream) {
  const void* h     = d_in[0];
  const void* x     = d_in[1];
  const void* ea    = d_in[2];
  const void* temb  = d_in[3];
  const void* We1   = d_in[4];
  const void* We1b  = d_in[5];
  const void* We2   = d_in[6];
  const void* We2b  = d_in[7];
  const void* Watt  = d_in[8];
  const void* Wattb = d_in[9];
  const void* Wx1   = d_in[10];
  const void* Wx1b  = d_in[11];
  const void* Wx2   = d_in[12];
  const void* Wx2b  = d_in[13];
  const void* Wh1   = d_in[14];
  const void* Wh1b  = d_in[15];
  const void* Wh2   = d_in[16];
  const void* Wh2b  = d_in[17];
  const int* eidx   = (const int*)d_in[18];
  char* ws = (char*)d_ws;

  // ws layout:
  u16* WprojT = (u16*)(ws + 0);          //  98,304
  u16* We2T   = (u16*)(ws + 98304);      //  32,768
  u16* Wx1T   = (u16*)(ws + 131072);     //  32,768
  u16* Wh1T   = (u16*)(ws + 163840);     //  65,536
  u16* Wh2T   = (u16*)(ws + 229376);     //  32,768  -> 262,144
  float* cagg = (float*)(ws + 262144);   // 800,000  -> 1,062,144
  int* flag   = (int*)(ws + 1062144);    //     256  -> 1,062,400
  // tierA: msgf fp32 [1,062,400 .. 26,662,400) + P2 [26,662,400 .. 39,462,400)
  // tierC: msgb bf16 [1,062,400 .. 13,862,400)
  bool tierA = (ws_size >= (size_t)39462400);
  float* msgf = (float*)(ws + 1062400);
  u16*   msgb = (u16*)(ws + 1062400);
  u16*   P2   = (u16*)(ws + 26662400);   // tierA only
  u16*   P13  = (u16*)d_out;             // staged in d_out bytes; k_node overwrites

  hipMemsetAsync(ws + 262144, 0, tierA ? 26400256 : 13600256, stream);
  k_probe<<<1, 64, 0, stream>>>((const u16*)h, flag);
  k_prep<0><<<512, 256, 0, stream>>>(flag, We1, We2, Wx1, Wh1, Wh2, WprojT, We2T, Wx1T, Wh1T, Wh2T);
  k_prep<1><<<512, 256, 0, stream>>>(flag, We1, We2, Wx1, Wh1, Wh2, WprojT, We2T, Wx1T, Wh1T, Wh2T);
  if (tierA){
    k_proj<0,1><<<(NN+63)/64, 256, 0, stream>>>(flag, h, temb, WprojT, We1b, P13, P2);
    k_proj<1,1><<<(NN+63)/64, 256, 0, stream>>>(flag, h, temb, WprojT, We1b, P13, P2);
    k_edge<0,1><<<EE/64, 256, 0, stream>>>(flag, x, ea, We1, h, We2b, Watt, Wattb, Wx1b, Wx2, Wx2b,
                                           eidx, P13, P2, WprojT, We2T, Wx1T, msgf, msgb, cagg);
    k_edge<1,1><<<EE/64, 256, 0, stream>>>(flag, x, ea, We1, h, We2b, Watt, Wattb, Wx1b, Wx2, Wx2b,
                                           eidx, P13, P2, WprojT, We2T, Wx1T, msgf, msgb, cagg);
    k_node<0,1><<<(NN+63)/64, 256, 0, stream>>>(flag, h, x, msgf, msgb, cagg, Wh1T, Wh1b, Wh2T, Wh2b, d_out);
    k_node<1,1><<<(NN+63)/64, 256, 0, stream>>>(flag, h, x, msgf, msgb, cagg, Wh1T, Wh1b, Wh2T, Wh2b, d_out);
  } else {
    k_proj<0,0><<<(NN+63)/64, 256, 0, stream>>>(flag, h, temb, WprojT, We1b, P13, P2);
    k_proj<1,0><<<(NN+63)/64, 256, 0, stream>>>(flag, h, temb, WprojT, We1b, P13, P2);
    k_edge<0,0><<<EE/64, 256, 0, stream>>>(flag, x, ea, We1, h, We2b, Watt, Wattb, Wx1b, Wx2, Wx2b,
                                           eidx, P13, P2, WprojT, We2T, Wx1T, msgf, msgb, cagg);
    k_edge<1,0><<<EE/64, 256, 0, stream>>>(flag, x, ea, We1, h, We2b, Watt, Wattb, Wx1b, Wx2, Wx2b,
                                           eidx, P13, P2, WprojT, We2T, Wx1T, msgf, msgb, cagg);
    k_node<0,0><<<(NN+63)/64, 256, 0, stream>>>(flag, h, x, msgf, msgb, cagg, Wh1T, Wh1b, Wh2T, Wh2b, d_out);
    k_node<1,0><<<(NN+63)/64, 256, 0, stream>>>(flag, h, x, msgf, msgb, cagg, Wh1T, Wh1b, Wh2T, Wh2b, d_out);
  }
}

// Round 6
// 1094.075 us; speedup vs baseline: 1.6994x; 1.0194x over previous
//
#include <hip/hip_runtime.h>

typedef unsigned short u16;
typedef unsigned int u32;
typedef __attribute__((ext_vector_type(8))) short short8;
typedef __attribute__((ext_vector_type(4))) float f32x4;

#define NN 50000
#define EE 800000

__device__ __forceinline__ float bf2f(u16 u){ union{u32 i; float f;} v; v.i=((u32)u)<<16; return v.f; }
__device__ __forceinline__ u16 f2bf(float f){ union{float f; u32 i;} v; v.f=f; u32 b=v.i; b += 0x7FFFu + ((b>>16)&1u); return (u16)(b>>16); }
__device__ __forceinline__ float sigmoidf_(float x){ return 1.0f/(1.0f+__expf(-x)); }

__device__ __forceinline__ void cvt8(uint4 q, float* f){
  f[0]=bf2f((u16)(q.x&0xFFFF)); f[1]=bf2f((u16)(q.x>>16));
  f[2]=bf2f((u16)(q.y&0xFFFF)); f[3]=bf2f((u16)(q.y>>16));
  f[4]=bf2f((u16)(q.z&0xFFFF)); f[5]=bf2f((u16)(q.z>>16));
  f[6]=bf2f((u16)(q.w&0xFFFF)); f[7]=bf2f((u16)(q.w>>16));
}
__device__ __forceinline__ uint4 pack8(const float* f){
  uint4 q;
  q.x=(u32)f2bf(f[0])|((u32)f2bf(f[1])<<16);
  q.y=(u32)f2bf(f[2])|((u32)f2bf(f[3])<<16);
  q.z=(u32)f2bf(f[4])|((u32)f2bf(f[5])<<16);
  q.w=(u32)f2bf(f[6])|((u32)f2bf(f[7])<<16);
  return q;
}

template<int FP32> struct IO;
template<> struct IO<0> {
  static __device__ __forceinline__ float ld(const void* p, int i){ return bf2f(((const u16*)p)[i]); }
  static __device__ __forceinline__ void ld8(const void* p, int i, float* f){
    cvt8(*(const uint4*)((const u16*)p + i), f);
  }
  static __device__ __forceinline__ void st(void* p, int i, float v){ ((u16*)p)[i] = f2bf(v); }
};
template<> struct IO<1> {
  static __device__ __forceinline__ float ld(const void* p, int i){ return ((const float*)p)[i]; }
  static __device__ __forceinline__ void ld8(const void* p, int i, float* f){
    f32x4 a = *(const f32x4*)((const float*)p + i);
    f32x4 b = *(const f32x4*)((const float*)p + i + 4);
    f[0]=a[0]; f[1]=a[1]; f[2]=a[2]; f[3]=a[3];
    f[4]=b[0]; f[5]=b[1]; f[6]=b[2]; f[7]=b[3];
  }
  static __device__ __forceinline__ void st(void* p, int i, float v){ ((float*)p)[i] = v; }
};

// bf16-pair atomic add via u32 CAS (fallback tier only)
__device__ __forceinline__ void atomic_add_bf16pair(u32* addr, float lo, float hi){
  u32 old = *addr, assumed;
  do {
    assumed = old;
    float flo = bf2f((u16)(assumed & 0xFFFFu)) + lo;
    float fhi = bf2f((u16)(assumed >> 16)) + hi;
    u32 newv = (u32)f2bf(flo) | ((u32)f2bf(fhi) << 16);
    if (newv == assumed) return;
    old = atomicCAS(addr, assumed, newv);
  } while (old != assumed);
}

// ---------------- dtype probe (proven R4) ----------------
__global__ void k_probe(const u16* __restrict__ hraw, int* __restrict__ flag){
  if (threadIdx.x==0 && blockIdx.x==0){
    float mx = 0.f; int zc = 0;
    for (int i = 0; i < 256; i += 2){
      u16 u = hraw[i];
      if (u == 0) zc++;
      float v = fabsf(bf2f(u));
      mx = fmaxf(mx, v);
    }
    flag[0] = (mx > 1e3f || zc > 32) ? 1 : 0;
  }
}

// ---------------- weight pack (output always bf16) ----------------
template<int FP32>
__global__ __launch_bounds__(256) void k_prep(
    const int* __restrict__ flag,
    const void* __restrict__ We1, const void* __restrict__ We2,
    const void* __restrict__ Wx1, const void* __restrict__ Wh1,
    const void* __restrict__ Wh2,
    u16* __restrict__ WprojT, u16* __restrict__ We2T, u16* __restrict__ Wx1T,
    u16* __restrict__ Wh1T, u16* __restrict__ Wh2T)
{
  if (flag[0] != FP32) return;
  int i = blockIdx.x*256 + threadIdx.x;
  if (i < 49152){
    int n = i/192, k = i%192; float v;
    if (n < 128) v = (k<128) ? IO<FP32>::ld(We1, k*128+n) : IO<FP32>::ld(We1, (265+k-128)*128+n);
    else         v = (k<128) ? IO<FP32>::ld(We1, (128+k)*128+(n-128)) : 0.f;
    WprojT[i] = f2bf(v);
  } else if (i < 65536){
    int j=i-49152; int n=j/128, k=j%128; We2T[j] = f2bf(IO<FP32>::ld(We2, k*128+n));
  } else if (i < 81920){
    int j=i-65536; int n=j/128, k=j%128; Wx1T[j] = f2bf(IO<FP32>::ld(Wx1, k*128+n));
  } else if (i < 114688){
    int j=i-81920; int n=j/256, k=j%256; Wh1T[j] = f2bf(IO<FP32>::ld(Wh1, k*128+n));
  } else if (i < 131072){
    int j=i-114688; int n=j/128, k=j%128; Wh2T[j] = f2bf(IO<FP32>::ld(Wh2, k*128+n));
  }
}

// ---------------- P13 (+P2 if WP2) ----------------
template<int FP32, int WP2>
__global__ __launch_bounds__(256) void k_proj(
    const int* __restrict__ flag,
    const void* __restrict__ h, const void* __restrict__ temb,
    const u16* __restrict__ WprojT, const void* __restrict__ We1b,
    u16* __restrict__ P13, u16* __restrict__ P2)
{
  if (flag[0] != FP32) return;
  constexpr int NT = WP2 ? 16 : 8;
  __shared__ __align__(16) u16 s_a[64][200];
  int tid = threadIdx.x; int nbase = blockIdx.x*64;
  {
    u32* p = (u32*)&s_a[0][0];
    for (int i = tid; i < 6400; i += 256) p[i] = 0u;
  }
  __syncthreads();
  {
    int r = tid>>2, p = tid&3; int node = nbase + r;
    if (node < NN){
      #pragma unroll
      for (int c=0;c<6;c++){
        int col = p*48 + c*8;
        float f[8];
        if (col<128) IO<FP32>::ld8(h, node*128 + col, f);
        else         IO<FP32>::ld8(temb, node*64 + (col-128), f);
        *(uint4*)&s_a[r][col] = pack8(f);
      }
    }
  }
  __syncthreads();
  int lane=tid&63, wid=tid>>6, quad=lane>>4, l15=lane&15, mb=wid*16;
  f32x4 acc[NT];
  #pragma unroll
  for (int nt=0;nt<NT;nt++) acc[nt]=(f32x4){0.f,0.f,0.f,0.f};
  #pragma unroll
  for (int ks=0;ks<6;ks++){
    short8 af = *(const short8*)&s_a[mb+l15][ks*32+quad*8];
    #pragma unroll
    for (int nt=0;nt<NT;nt++){
      short8 bfr = *(const short8*)(WprojT + (nt*16+l15)*192 + ks*32+quad*8);
      acc[nt] = __builtin_amdgcn_mfma_f32_16x16x32_bf16(af, bfr, acc[nt], 0,0,0);
    }
  }
  #pragma unroll
  for (int r=0;r<4;r++){
    int node = nbase + mb + quad*4 + r;
    if (node < NN){
      #pragma unroll
      for (int nt=0;nt<NT;nt++){
        int colg = nt*16 + l15;
        float v = acc[nt][r];
        if (colg < 128) P13[node*128+colg] = f2bf(v + IO<FP32>::ld(We1b, colg));
        else if (WP2)   P2[node*128+(colg-128)] = f2bf(v);
      }
    }
  }
}

// ---------------- fused edge kernel: 64 edges/block, BARRIER-FREE ----------------
// Every LDS row range [16w,16w+16) is written and read only by wave w; no __syncthreads.
template<int FP32, int TIERA>
__global__ __launch_bounds__(256) void k_edge(
    const int* __restrict__ flag,
    const void* __restrict__ x, const void* __restrict__ ea,
    const void* __restrict__ We1, const void* __restrict__ h,
    const void* __restrict__ We2b, const void* __restrict__ Watt, const void* __restrict__ Wattb,
    const void* __restrict__ Wx1b, const void* __restrict__ Wx2, const void* __restrict__ Wx2b,
    const int* __restrict__ eidx,
    const u16* __restrict__ P13, const u16* __restrict__ P2,
    const u16* __restrict__ WprojT,
    const u16* __restrict__ We2T, const u16* __restrict__ Wx1T,
    float* __restrict__ msgf, u16* __restrict__ msgb, float* __restrict__ cagg)
{
  if (flag[0] != FP32) return;
  __shared__ int s_dst[64];
  __shared__ float s_dif[64][3];
  __shared__ __align__(16) u16 s_hid[64][136];
  __shared__ __align__(16) u16 s_m[64][136];
  __shared__ __align__(16) u16 s_hd[TIERA?1:64][136];
  int tid = threadIdx.x;
  int ebase = blockIdx.x*64;
  // ---- phase A (wave-local rows): el = tid>>2 lies in this wave's row range
  {
    int el = tid>>2, p = tid&3;
    int srcI = eidx[ebase+el], dstI = eidx[EE+ebase+el];
    float d0 = IO<FP32>::ld(x, srcI*3+0) - IO<FP32>::ld(x, dstI*3+0);
    float d1 = IO<FP32>::ld(x, srcI*3+1) - IO<FP32>::ld(x, dstI*3+1);
    float d2 = IO<FP32>::ld(x, srcI*3+2) - IO<FP32>::ld(x, dstI*3+2);
    float dsq = d0*d0 + d1*d1 + d2*d2;
    if (p==0){ s_dst[el]=dstI; s_dif[el][0]=d0; s_dif[el][1]=d1; s_dif[el][2]=d2; }
    float eav[8]; IO<FP32>::ld8(ea, (ebase+el)*8, eav);
    const u16* p13r = P13 + srcI*128;
    #pragma unroll
    for (int c=0;c<4;c++){
      int col = p*32 + c*8;
      float fw[8], pre[8];
      cvt8(*(const uint4*)(p13r+col), pre);
      IO<FP32>::ld8(We1, 256*128 + col, fw);
      #pragma unroll
      for (int i2=0;i2<8;i2++) pre[i2] += dsq*fw[i2];
      #pragma unroll
      for (int t=0;t<8;t++){
        IO<FP32>::ld8(We1, (257+t)*128 + col, fw);
        #pragma unroll
        for (int i2=0;i2<8;i2++) pre[i2] += eav[t]*fw[i2];
      }
      if constexpr (TIERA){
        float fb[8]; cvt8(*(const uint4*)(P2 + dstI*128 + col), fb);
        #pragma unroll
        for (int i2=0;i2<8;i2++){ float u = pre[i2]+fb[i2]; pre[i2] = u*sigmoidf_(u); }
      }
      *(uint4*)&s_hid[el][col] = pack8(pre);
      if constexpr (!TIERA){
        float hd[8]; IO<FP32>::ld8(h, dstI*128 + col, hd);
        *(uint4*)&s_hd[el][col] = pack8(hd);
      }
    }
  }
  int lane=tid&63, wid=tid>>6, quad=lane>>4, l15=lane&15, mb=wid*16;
  if constexpr (!TIERA){
    f32x4 accg[8];
    #pragma unroll
    for (int nt=0;nt<8;nt++) accg[nt]=(f32x4){0.f,0.f,0.f,0.f};
    #pragma unroll
    for (int ks=0;ks<4;ks++){
      short8 af = *(const short8*)&s_hd[mb+l15][ks*32+quad*8];
      #pragma unroll
      for (int nt=0;nt<8;nt++){
        short8 bfr = *(const short8*)(WprojT + (128 + nt*16+l15)*192 + ks*32+quad*8);
        accg[nt] = __builtin_amdgcn_mfma_f32_16x16x32_bf16(af, bfr, accg[nt], 0,0,0);
      }
    }
    #pragma unroll
    for (int r=0;r<4;r++){
      int row = mb + quad*4 + r;
      #pragma unroll
      for (int nt=0;nt<8;nt++){
        int col = nt*16+l15;
        float u = bf2f(s_hid[row][col]) + accg[nt][r];
        u = u*sigmoidf_(u);
        s_hid[row][col] = f2bf(u);
      }
    }
  }
  // ---- GEMM1: m_pre = hid @ We2   (reads own wave's rows)
  f32x4 acc[8];
  #pragma unroll
  for (int nt=0;nt<8;nt++) acc[nt]=(f32x4){0.f,0.f,0.f,0.f};
  #pragma unroll
  for (int ks=0;ks<4;ks++){
    short8 af = *(const short8*)&s_hid[mb+l15][ks*32+quad*8];
    #pragma unroll
    for (int nt=0;nt<8;nt++){
      short8 bfr = *(const short8*)(We2T + (nt*16+l15)*128 + ks*32+quad*8);
      acc[nt] = __builtin_amdgcn_mfma_f32_16x16x32_bf16(af, bfr, acc[nt], 0,0,0);
    }
  }
  // ---- epilogue: attention gate; write s_m (own rows) + atomic msg_agg
  float b2v[8], wav[8];
  #pragma unroll
  for (int nt=0;nt<8;nt++){ b2v[nt]=IO<FP32>::ld(We2b, nt*16+l15); wav[nt]=IO<FP32>::ld(Watt, nt*16+l15); }
  float attb = IO<FP32>::ld(Wattb, 0);
  float mval[8][4]; float dotr[4];
  #pragma unroll
  for (int r=0;r<4;r++){
    float s=0.f;
    #pragma unroll
    for (int nt=0;nt<8;nt++){ mval[nt][r]=acc[nt][r]+b2v[nt]; s += mval[nt][r]*wav[nt]; }
    dotr[r]=s;
  }
  #pragma unroll
  for (int off=1;off<16;off<<=1){
    #pragma unroll
    for (int r=0;r<4;r++) dotr[r] += __shfl_xor(dotr[r], off);
  }
  #pragma unroll
  for (int r=0;r<4;r++){
    float att = sigmoidf_(dotr[r]+attb);
    int erow = mb + quad*4 + r;
    int dstN = s_dst[erow];
    #pragma unroll
    for (int nt=0;nt<8;nt++){
      float v = mval[nt][r]*att;
      mval[nt][r] = v;
      s_m[erow][nt*16+l15] = f2bf(v);
      if constexpr (TIERA){
        atomicAdd(msgf + dstN*128 + nt*16 + l15, v);
      }
    }
    if constexpr (!TIERA){
      #pragma unroll
      for (int nt=0;nt<8;nt++){
        float part = __shfl_xor(mval[nt][r], 1);
        if ((l15 & 1) == 0){
          atomic_add_bf16pair((u32*)(msgb + dstN*128 + nt*16 + l15), mval[nt][r], part);
        }
      }
    }
  }
  // ---- GEMM2: ch_pre = m @ Wx1  (reads own wave's rows)
  f32x4 acc2[8];
  #pragma unroll
  for (int nt=0;nt<8;nt++) acc2[nt]=(f32x4){0.f,0.f,0.f,0.f};
  #pragma unroll
  for (int ks=0;ks<4;ks++){
    short8 af = *(const short8*)&s_m[mb+l15][ks*32+quad*8];
    #pragma unroll
    for (int nt=0;nt<8;nt++){
      short8 bfr = *(const short8*)(Wx1T + (nt*16+l15)*128 + ks*32+quad*8);
      acc2[nt] = __builtin_amdgcn_mfma_f32_16x16x32_bf16(af, bfr, acc2[nt], 0,0,0);
    }
  }
  // ---- epilogue: coord weight + fp32 atomics
  float bx1v[8], wx2v[8];
  #pragma unroll
  for (int nt=0;nt<8;nt++){ bx1v[nt]=IO<FP32>::ld(Wx1b, nt*16+l15); wx2v[nt]=IO<FP32>::ld(Wx2, nt*16+l15); }
  float bx2f = IO<FP32>::ld(Wx2b, 0);
  float dc[4];
  #pragma unroll
  for (int r=0;r<4;r++){
    float s=0.f;
    #pragma unroll
    for (int nt=0;nt<8;nt++){
      float u = acc2[nt][r] + bx1v[nt];
      u = u*sigmoidf_(u);
      s += u*wx2v[nt];
    }
    dc[r]=s;
  }
  #pragma unroll
  for (int off=1;off<16;off<<=1){
    #pragma unroll
    for (int r=0;r<4;r++) dc[r] += __shfl_xor(dc[r], off);
  }
  #pragma unroll
  for (int r=0;r<4;r++){
    float cw = tanhf(dc[r]+bx2f);
    if (l15==0){
      int erow = mb + quad*4 + r;
      int dstN = s_dst[erow];
      atomicAdd(&cagg[dstN*4+0], s_dif[erow][0]*cw);
      atomicAdd(&cagg[dstN*4+1], s_dif[erow][1]*cw);
      atomicAdd(&cagg[dstN*4+2], s_dif[erow][2]*cw);
      atomicAdd(&cagg[dstN*4+3], 1.0f);
    }
  }
}

// ---------------- node update ----------------
template<int FP32, int MSGF>
__global__ __launch_bounds__(256) void k_node(
    const int* __restrict__ flag,
    const void* __restrict__ h, const void* __restrict__ x,
    const float* __restrict__ msgf, const u16* __restrict__ msgb,
    const float* __restrict__ cagg,
    const u16* __restrict__ Wh1T, const void* __restrict__ Wh1b,
    const u16* __restrict__ Wh2T, const void* __restrict__ Wh2b,
    void* __restrict__ out)
{
  if (flag[0] != FP32) return;
  __shared__ __align__(16) u16 s_a[64][264];
  __shared__ __align__(16) u16 s_u[64][136];
  int tid = threadIdx.x; int nbase = blockIdx.x*64;
  {
    u32* p1 = (u32*)&s_a[0][0];
    for (int i = tid; i < 8448; i += 256) p1[i] = 0u;
  }
  __syncthreads();
  {
    int r = tid>>2, p = tid&3; int node = nbase + r;
    if (node < NN){
      #pragma unroll
      for (int c=0;c<8;c++){
        int col = p*64 + c*8;
        if (col < 128){
          float f[8]; IO<FP32>::ld8(h, node*128 + col, f);
          *(uint4*)&s_a[r][col] = pack8(f);
        } else if (MSGF){
          const float* mp = msgf + node*128 + (col-128);
          float f[8];
          *(f32x4*)&f[0] = *(const f32x4*)mp;
          *(f32x4*)&f[4] = *(const f32x4*)(mp+4);
          *(uint4*)&s_a[r][col] = pack8(f);
        } else {
          *(uint4*)&s_a[r][col] = *(const uint4*)(msgb + node*128 + (col-128));
        }
      }
    }
  }
  __syncthreads();
  int lane=tid&63, wid=tid>>6, quad=lane>>4, l15=lane&15, mb=wid*16;
  f32x4 acc[8];
  #pragma unroll
  for (int nt=0;nt<8;nt++) acc[nt]=(f32x4){0.f,0.f,0.f,0.f};
  #pragma unroll
  for (int ks=0;ks<8;ks++){
    short8 af = *(const short8*)&s_a[mb+l15][ks*32+quad*8];
    #pragma unroll
    for (int nt=0;nt<8;nt++){
      short8 bfr = *(const short8*)(Wh1T + (nt*16+l15)*256 + ks*32+quad*8);
      acc[nt] = __builtin_amdgcn_mfma_f32_16x16x32_bf16(af, bfr, acc[nt], 0,0,0);
    }
  }
  #pragma unroll
  for (int r=0;r<4;r++){
    int row = mb + quad*4 + r;
    #pragma unroll
    for (int nt=0;nt<8;nt++){
      int col = nt*16+l15;
      float u = acc[nt][r] + IO<FP32>::ld(Wh1b, col);
      u = u*sigmoidf_(u);
      s_u[row][col] = f2bf(u);
    }
  }
  f32x4 acc2[8];
  #pragma unroll
  for (int nt=0;nt<8;nt++) acc2[nt]=(f32x4){0.f,0.f,0.f,0.f};
  #pragma unroll
  for (int ks=0;ks<4;ks++){
    short8 af = *(const short8*)&s_u[mb+l15][ks*32+quad*8];
    #pragma unroll
    for (int nt=0;nt<8;nt++){
      short8 bfr = *(const short8*)(Wh2T + (nt*16+l15)*128 + ks*32+quad*8);
      acc2[nt] = __builtin_amdgcn_mfma_f32_16x16x32_bf16(af, bfr, acc2[nt], 0,0,0);
    }
  }
  #pragma unroll
  for (int r=0;r<4;r++){
    int node = nbase + mb + quad*4 + r;
    if (node < NN){
      #pragma unroll
      for (int nt=0;nt<8;nt++){
        int col = nt*16+l15;
        float v = IO<FP32>::ld(h, node*128+col) + acc2[nt][r] + IO<FP32>::ld(Wh2b, col);
        IO<FP32>::st(out, node*128+col, v);
      }
    }
  }
  if (tid < 64){
    int node = nbase + tid;
    if (node < NN){
      float inv = 1.0f/(cagg[node*4+3] + 1.0f);
      #pragma unroll
      for (int c=0;c<3;c++){
        float v = IO<FP32>::ld(x, node*3+c) + cagg[node*4+c]*inv;
        IO<FP32>::st(out, NN*128 + node*3 + c, v);
      }
    }
  }
}

extern "C" void kernel_launch(void* const* d_in, const int* in_sizes, int n_in,
                              void* d_out, int out_size, void* d_ws, size_t ws_size,
                              hipStream_t stream) {
  const void* h     = d_in[0];
  const void* x     = d_in[1];
  const void* ea    = d_in[2];
  const void* temb  = d_in[3];
  const void* We1   = d_in[4];
  const void* We1b  = d_in[5];
  const void* We2   = d_in[6];
  const void* We2b  = d_in[7];
  const void* Watt  = d_in[8];
  const void* Wattb = d_in[9];
  const void* Wx1   = d_in[10];
  const void* Wx1b  = d_in[11];
  const void* Wx2   = d_in[12];
  const void* Wx2b  = d_in[13];
  const void* Wh1   = d_in[14];
  const void* Wh1b  = d_in[15];
  const void* Wh2   = d_in[16];
  const void* Wh2b  = d_in[17];
  const int* eidx   = (const int*)d_in[18];
  char* ws = (char*)d_ws;

  u16* WprojT = (u16*)(ws + 0);          //  98,304
  u16* We2T   = (u16*)(ws + 98304);      //  32,768
  u16* Wx1T   = (u16*)(ws + 131072);     //  32,768
  u16* Wh1T   = (u16*)(ws + 163840);     //  65,536
  u16* Wh2T   = (u16*)(ws + 229376);     //  32,768  -> 262,144
  float* cagg = (float*)(ws + 262144);   // 800,000  -> 1,062,144
  int* flag   = (int*)(ws + 1062144);    //     256  -> 1,062,400
  bool tierA = (ws_size >= (size_t)39462400);
  float* msgf = (float*)(ws + 1062400);
  u16*   msgb = (u16*)(ws + 1062400);
  u16*   P2   = (u16*)(ws + 26662400);   // tierA only
  u16*   P13  = (u16*)d_out;

  hipMemsetAsync(ws + 262144, 0, tierA ? 26400256 : 13600256, stream);
  k_probe<<<1, 64, 0, stream>>>((const u16*)h, flag);
  k_prep<0><<<512, 256, 0, stream>>>(flag, We1, We2, Wx1, Wh1, Wh2, WprojT, We2T, Wx1T, Wh1T, Wh2T);
  k_prep<1><<<512, 256, 0, stream>>>(flag, We1, We2, Wx1, Wh1, Wh2, WprojT, We2T, Wx1T, Wh1T, Wh2T);
  if (tierA){
    k_proj<0,1><<<(NN+63)/64, 256, 0, stream>>>(flag, h, temb, WprojT, We1b, P13, P2);
    k_proj<1,1><<<(NN+63)/64, 256, 0, stream>>>(flag, h, temb, WprojT, We1b, P13, P2);
    k_edge<0,1><<<EE/64, 256, 0, stream>>>(flag, x, ea, We1, h, We2b, Watt, Wattb, Wx1b, Wx2, Wx2b,
                                           eidx, P13, P2, WprojT, We2T, Wx1T, msgf, msgb, cagg);
    k_edge<1,1><<<EE/64, 256, 0, stream>>>(flag, x, ea, We1, h, We2b, Watt, Wattb, Wx1b, Wx2, Wx2b,
                                           eidx, P13, P2, WprojT, We2T, Wx1T, msgf, msgb, cagg);
    k_node<0,1><<<(NN+63)/64, 256, 0, stream>>>(flag, h, x, msgf, msgb, cagg, Wh1T, Wh1b, Wh2T, Wh2b, d_out);
    k_node<1,1><<<(NN+63)/64, 256, 0, stream>>>(flag, h, x, msgf, msgb, cagg, Wh1T, Wh1b, Wh2T, Wh2b, d_out);
  } else {
    k_proj<0,0><<<(NN+63)/64, 256, 0, stream>>>(flag, h, temb, WprojT, We1b, P13, P2);
    k_proj<1,0><<<(NN+63)/64, 256, 0, stream>>>(flag, h, temb, WprojT, We1b, P13, P2);
    k_edge<0,0><<<EE/64, 256, 0, stream>>>(flag, x, ea, We1, h, We2b, Watt, Wattb, Wx1b, Wx2, Wx2b,
                                           eidx, P13, P2, WprojT, We2T, Wx1T, msgf, msgb, cagg);
    k_edge<1,0><<<EE/64, 256, 0, stream>>>(flag, x, ea, We1, h, We2b, Watt, Wattb, Wx1b, Wx2, Wx2b,
                                           eidx, P13, P2, WprojT, We2T, Wx1T, msgf, msgb, cagg);
    k_node<0,0><<<(NN+63)/64, 256, 0, stream>>>(flag, h, x, msgf, msgb, cagg, Wh1T, Wh1b, Wh2T, Wh2b, d_out);
    k_node<1,0><<<(NN+63)/64, 256, 0, stream>>>(flag, h, x, msgf, msgb, cagg, Wh1T, Wh1b, Wh2T, Wh2b, d_out);
  }
}

// Round 7
// 843.392 us; speedup vs baseline: 2.2045x; 1.2972x over previous
//
#include <hip/hip_runtime.h>

typedef unsigned short u16;
typedef unsigned int u32;
typedef __attribute__((ext_vector_type(8))) short short8;
typedef __attribute__((ext_vector_type(4))) float f32x4;

#define NN 50000
#define EE 800000

__device__ __forceinline__ float bf2f(u16 u){ union{u32 i; float f;} v; v.i=((u32)u)<<16; return v.f; }
__device__ __forceinline__ u16 f2bf(float f){ union{float f; u32 i;} v; v.f=f; u32 b=v.i; b += 0x7FFFu + ((b>>16)&1u); return (u16)(b>>16); }
__device__ __forceinline__ float sigmoidf_(float x){ return 1.0f/(1.0f+__expf(-x)); }

__device__ __forceinline__ void cvt8(uint4 q, float* f){
  f[0]=bf2f((u16)(q.x&0xFFFF)); f[1]=bf2f((u16)(q.x>>16));
  f[2]=bf2f((u16)(q.y&0xFFFF)); f[3]=bf2f((u16)(q.y>>16));
  f[4]=bf2f((u16)(q.z&0xFFFF)); f[5]=bf2f((u16)(q.z>>16));
  f[6]=bf2f((u16)(q.w&0xFFFF)); f[7]=bf2f((u16)(q.w>>16));
}
__device__ __forceinline__ uint4 pack8(const float* f){
  uint4 q;
  q.x=(u32)f2bf(f[0])|((u32)f2bf(f[1])<<16);
  q.y=(u32)f2bf(f[2])|((u32)f2bf(f[3])<<16);
  q.z=(u32)f2bf(f[4])|((u32)f2bf(f[5])<<16);
  q.w=(u32)f2bf(f[6])|((u32)f2bf(f[7])<<16);
  return q;
}

template<int FP32> struct IO;
template<> struct IO<0> {
  static __device__ __forceinline__ float ld(const void* p, int i){ return bf2f(((const u16*)p)[i]); }
  static __device__ __forceinline__ void ld8(const void* p, int i, float* f){
    cvt8(*(const uint4*)((const u16*)p + i), f);
  }
  static __device__ __forceinline__ void st(void* p, int i, float v){ ((u16*)p)[i] = f2bf(v); }
};
template<> struct IO<1> {
  static __device__ __forceinline__ float ld(const void* p, int i){ return ((const float*)p)[i]; }
  static __device__ __forceinline__ void ld8(const void* p, int i, float* f){
    f32x4 a = *(const f32x4*)((const float*)p + i);
    f32x4 b = *(const f32x4*)((const float*)p + i + 4);
    f[0]=a[0]; f[1]=a[1]; f[2]=a[2]; f[3]=a[3];
    f[4]=b[0]; f[5]=b[1]; f[6]=b[2]; f[7]=b[3];
  }
  static __device__ __forceinline__ void st(void* p, int i, float v){ ((float*)p)[i] = v; }
};

// bf16-pair atomic add via u32 CAS (fallback tier only)
__device__ __forceinline__ void atomic_add_bf16pair(u32* addr, float lo, float hi){
  u32 old = *addr, assumed;
  do {
    assumed = old;
    float flo = bf2f((u16)(assumed & 0xFFFFu)) + lo;
    float fhi = bf2f((u16)(assumed >> 16)) + hi;
    u32 newv = (u32)f2bf(flo) | ((u32)f2bf(fhi) << 16);
    if (newv == assumed) return;
    old = atomicCAS(addr, assumed, newv);
  } while (old != assumed);
}

// ---------------- dtype probe (proven R4) ----------------
__global__ void k_probe(const u16* __restrict__ hraw, int* __restrict__ flag){
  if (threadIdx.x==0 && blockIdx.x==0){
    float mx = 0.f; int zc = 0;
    for (int i = 0; i < 256; i += 2){
      u16 u = hraw[i];
      if (u == 0) zc++;
      float v = fabsf(bf2f(u));
      mx = fmaxf(mx, v);
    }
    flag[0] = (mx > 1e3f || zc > 32) ? 1 : 0;
  }
}

// ---------------- weight pack (output always bf16) ----------------
// WprojT [256 n][192 k] (P13 / P2 projections), We2T/Wx1T/Wh2T [128][128], Wh1T [128][256],
// Wrk9T [128 n][32 k]: k=0 -> We1[256][n] (dist), k=1..8 -> We1[256+k][n] (edge_attr), else 0.
template<int FP32>
__global__ __launch_bounds__(256) void k_prep(
    const int* __restrict__ flag,
    const void* __restrict__ We1, const void* __restrict__ We2,
    const void* __restrict__ Wx1, const void* __restrict__ Wh1,
    const void* __restrict__ Wh2,
    u16* __restrict__ WprojT, u16* __restrict__ We2T, u16* __restrict__ Wx1T,
    u16* __restrict__ Wh1T, u16* __restrict__ Wh2T, u16* __restrict__ Wrk9T)
{
  if (flag[0] != FP32) return;
  int i = blockIdx.x*256 + threadIdx.x;
  if (i < 49152){
    int n = i/192, k = i%192; float v;
    if (n < 128) v = (k<128) ? IO<FP32>::ld(We1, k*128+n) : IO<FP32>::ld(We1, (265+k-128)*128+n);
    else         v = (k<128) ? IO<FP32>::ld(We1, (128+k)*128+(n-128)) : 0.f;
    WprojT[i] = f2bf(v);
  } else if (i < 65536){
    int j=i-49152; int n=j/128, k=j%128; We2T[j] = f2bf(IO<FP32>::ld(We2, k*128+n));
  } else if (i < 81920){
    int j=i-65536; int n=j/128, k=j%128; Wx1T[j] = f2bf(IO<FP32>::ld(Wx1, k*128+n));
  } else if (i < 114688){
    int j=i-81920; int n=j/256, k=j%256; Wh1T[j] = f2bf(IO<FP32>::ld(Wh1, k*128+n));
  } else if (i < 131072){
    int j=i-114688; int n=j/128, k=j%128; Wh2T[j] = f2bf(IO<FP32>::ld(Wh2, k*128+n));
  } else if (i < 135168){
    int j=i-131072; int n=j/32, k=j%32;
    float v = (k<=8) ? IO<FP32>::ld(We1, (256+k)*128+n) : 0.f;
    Wrk9T[j] = f2bf(v);
  }
}

// ---------------- P13 (+P2 if WP2) ----------------
template<int FP32, int WP2>
__global__ __launch_bounds__(256) void k_proj(
    const int* __restrict__ flag,
    const void* __restrict__ h, const void* __restrict__ temb,
    const u16* __restrict__ WprojT, const void* __restrict__ We1b,
    u16* __restrict__ P13, u16* __restrict__ P2)
{
  if (flag[0] != FP32) return;
  constexpr int NT = WP2 ? 16 : 8;
  __shared__ __align__(16) u16 s_a[64][200];
  int tid = threadIdx.x; int nbase = blockIdx.x*64;
  {
    u32* p = (u32*)&s_a[0][0];
    for (int i = tid; i < 6400; i += 256) p[i] = 0u;
  }
  __syncthreads();
  {
    int r = tid>>2, p = tid&3; int node = nbase + r;
    if (node < NN){
      #pragma unroll
      for (int c=0;c<6;c++){
        int col = p*48 + c*8;
        float f[8];
        if (col<128) IO<FP32>::ld8(h, node*128 + col, f);
        else         IO<FP32>::ld8(temb, node*64 + (col-128), f);
        *(uint4*)&s_a[r][col] = pack8(f);
      }
    }
  }
  __syncthreads();
  int lane=tid&63, wid=tid>>6, quad=lane>>4, l15=lane&15, mb=wid*16;
  f32x4 acc[NT];
  #pragma unroll
  for (int nt=0;nt<NT;nt++) acc[nt]=(f32x4){0.f,0.f,0.f,0.f};
  #pragma unroll
  for (int ks=0;ks<6;ks++){
    short8 af = *(const short8*)&s_a[mb+l15][ks*32+quad*8];
    #pragma unroll
    for (int nt=0;nt<NT;nt++){
      short8 bfr = *(const short8*)(WprojT + (nt*16+l15)*192 + ks*32+quad*8);
      acc[nt] = __builtin_amdgcn_mfma_f32_16x16x32_bf16(af, bfr, acc[nt], 0,0,0);
    }
  }
  #pragma unroll
  for (int r=0;r<4;r++){
    int node = nbase + mb + quad*4 + r;
    if (node < NN){
      #pragma unroll
      for (int nt=0;nt<NT;nt++){
        int colg = nt*16 + l15;
        float v = acc[nt][r];
        if (colg < 128) P13[node*128+colg] = f2bf(v + IO<FP32>::ld(We1b, colg));
        else if (WP2)   P2[node*128+(colg-128)] = f2bf(v);
      }
    }
  }
}

// ---------------- fused edge kernel: 64 edges/block, barrier-free ----------------
// TIERA=1: P2 precomputed; rank-9 (dist+edge_attr) term via MFMA with Wrk9T; m overlaid in s_hid.
// TIERA=0: R5/R6-proven fallback path (h[dst] gather + GEMM-G + CAS msg).
template<int FP32, int TIERA>
__global__ __launch_bounds__(256, 6) void k_edge(
    const int* __restrict__ flag,
    const void* __restrict__ x, const void* __restrict__ ea,
    const void* __restrict__ We1, const void* __restrict__ h,
    const void* __restrict__ We2b, const void* __restrict__ Watt, const void* __restrict__ Wattb,
    const void* __restrict__ Wx1b, const void* __restrict__ Wx2, const void* __restrict__ Wx2b,
    const int* __restrict__ eidx,
    const u16* __restrict__ P13, const u16* __restrict__ P2,
    const u16* __restrict__ WprojT, const u16* __restrict__ Wrk9T,
    const u16* __restrict__ We2T, const u16* __restrict__ Wx1T,
    float* __restrict__ msgf, u16* __restrict__ msgb, float* __restrict__ cagg)
{
  if (flag[0] != FP32) return;
  __shared__ int s_dst[64];
  __shared__ float s_dif[64][3];
  __shared__ __align__(16) u16 s_hid[64][136];
  __shared__ __align__(16) u16 s_att[TIERA?64:1][40];   // [edge][k] rank-9 A operand, K=32 zero-padded
  __shared__ __align__(16) u16 s_m[TIERA?1:64][136];
  __shared__ __align__(16) u16 s_hd[TIERA?1:64][136];
  int tid = threadIdx.x;
  int ebase = blockIdx.x*64;
  // ---- phase A (wave-local rows: el = tid>>2 is in this wave's 16-row range)
  {
    int el = tid>>2, p = tid&3;
    int srcI = eidx[ebase+el], dstI = eidx[EE+ebase+el];
    float d0 = IO<FP32>::ld(x, srcI*3+0) - IO<FP32>::ld(x, dstI*3+0);
    float d1 = IO<FP32>::ld(x, srcI*3+1) - IO<FP32>::ld(x, dstI*3+1);
    float d2 = IO<FP32>::ld(x, srcI*3+2) - IO<FP32>::ld(x, dstI*3+2);
    float dsq = d0*d0 + d1*d1 + d2*d2;
    if (p==0){ s_dst[el]=dstI; s_dif[el][0]=d0; s_dif[el][1]=d1; s_dif[el][2]=d2; }
    if constexpr (TIERA){
      if (p < 2){
        float eav[8]; IO<FP32>::ld8(ea, (ebase+el)*8, eav);
        float f9[8];
        if (p==0){ f9[0]=dsq; for (int t=0;t<7;t++) f9[1+t]=eav[t]; }
        else { f9[0]=eav[7]; for (int t=1;t<8;t++) f9[t]=0.f; }
        *(uint4*)&s_att[el][p*8] = pack8(f9);
      } else {
        *(uint4*)&s_att[el][p*8] = make_uint4(0,0,0,0);
      }
      const u16* p13r = P13 + srcI*128;
      const u16* p2r  = P2  + dstI*128;
      #pragma unroll
      for (int c=0;c<4;c++){
        int col = p*32 + c*8;
        float fa[8], fb[8];
        cvt8(*(const uint4*)(p13r+col), fa);
        cvt8(*(const uint4*)(p2r+col),  fb);
        #pragma unroll
        for (int i2=0;i2<8;i2++) fa[i2] += fb[i2];
        *(uint4*)&s_hid[el][col] = pack8(fa);
      }
    } else {
      float eav[8]; IO<FP32>::ld8(ea, (ebase+el)*8, eav);
      const u16* p13r = P13 + srcI*128;
      #pragma unroll
      for (int c=0;c<4;c++){
        int col = p*32 + c*8;
        float fw[8], pre[8];
        cvt8(*(const uint4*)(p13r+col), pre);
        IO<FP32>::ld8(We1, 256*128 + col, fw);
        #pragma unroll
        for (int i2=0;i2<8;i2++) pre[i2] += dsq*fw[i2];
        #pragma unroll
        for (int t=0;t<8;t++){
          IO<FP32>::ld8(We1, (257+t)*128 + col, fw);
          #pragma unroll
          for (int i2=0;i2<8;i2++) pre[i2] += eav[t]*fw[i2];
        }
        *(uint4*)&s_hid[el][col] = pack8(pre);
        float hd[8]; IO<FP32>::ld8(h, dstI*128 + col, hd);
        *(uint4*)&s_hd[el][col] = pack8(hd);
      }
    }
  }
  int lane=tid&63, wid=tid>>6, quad=lane>>4, l15=lane&15, mb=wid*16;
  if constexpr (TIERA){
    // ---- rank-9 MFMA: [dsq, ea] @ We1[256:265,:]; fold into s_hid + silu
    f32x4 acc9[8];
    #pragma unroll
    for (int nt=0;nt<8;nt++) acc9[nt]=(f32x4){0.f,0.f,0.f,0.f};
    short8 a9 = *(const short8*)&s_att[mb+l15][quad*8];
    #pragma unroll
    for (int nt=0;nt<8;nt++){
      short8 bfr = *(const short8*)(Wrk9T + (nt*16+l15)*32 + quad*8);
      acc9[nt] = __builtin_amdgcn_mfma_f32_16x16x32_bf16(a9, bfr, acc9[nt], 0,0,0);
    }
    #pragma unroll
    for (int r=0;r<4;r++){
      int row = mb + quad*4 + r;
      #pragma unroll
      for (int nt=0;nt<8;nt++){
        int col = nt*16+l15;
        float u = bf2f(s_hid[row][col]) + acc9[nt][r];
        u = u*sigmoidf_(u);
        s_hid[row][col] = f2bf(u);
      }
    }
  } else {
    // GEMM-G: h_dst @ We1[128:256], fold + silu
    f32x4 accg[8];
    #pragma unroll
    for (int nt=0;nt<8;nt++) accg[nt]=(f32x4){0.f,0.f,0.f,0.f};
    #pragma unroll
    for (int ks=0;ks<4;ks++){
      short8 af = *(const short8*)&s_hd[mb+l15][ks*32+quad*8];
      #pragma unroll
      for (int nt=0;nt<8;nt++){
        short8 bfr = *(const short8*)(WprojT + (128 + nt*16+l15)*192 + ks*32+quad*8);
        accg[nt] = __builtin_amdgcn_mfma_f32_16x16x32_bf16(af, bfr, accg[nt], 0,0,0);
      }
    }
    #pragma unroll
    for (int r=0;r<4;r++){
      int row = mb + quad*4 + r;
      #pragma unroll
      for (int nt=0;nt<8;nt++){
        int col = nt*16+l15;
        float u = bf2f(s_hid[row][col]) + accg[nt][r];
        u = u*sigmoidf_(u);
        s_hid[row][col] = f2bf(u);
      }
    }
  }
  // ---- GEMM1: m_pre = hid @ We2 (own rows)
  f32x4 acc[8];
  #pragma unroll
  for (int nt=0;nt<8;nt++) acc[nt]=(f32x4){0.f,0.f,0.f,0.f};
  #pragma unroll
  for (int ks=0;ks<4;ks++){
    short8 af = *(const short8*)&s_hid[mb+l15][ks*32+quad*8];
    #pragma unroll
    for (int nt=0;nt<8;nt++){
      short8 bfr = *(const short8*)(We2T + (nt*16+l15)*128 + ks*32+quad*8);
      acc[nt] = __builtin_amdgcn_mfma_f32_16x16x32_bf16(af, bfr, acc[nt], 0,0,0);
    }
  }
  // ---- epilogue: attention gate; m -> s_hid (overlay, own rows) + atomic msg
  float b2v[8], wav[8];
  #pragma unroll
  for (int nt=0;nt<8;nt++){ b2v[nt]=IO<FP32>::ld(We2b, nt*16+l15); wav[nt]=IO<FP32>::ld(Watt, nt*16+l15); }
  float attb = IO<FP32>::ld(Wattb, 0);
  float mval[8][4]; float dotr[4];
  #pragma unroll
  for (int r=0;r<4;r++){
    float s=0.f;
    #pragma unroll
    for (int nt=0;nt<8;nt++){ mval[nt][r]=acc[nt][r]+b2v[nt]; s += mval[nt][r]*wav[nt]; }
    dotr[r]=s;
  }
  #pragma unroll
  for (int off=1;off<16;off<<=1){
    #pragma unroll
    for (int r=0;r<4;r++) dotr[r] += __shfl_xor(dotr[r], off);
  }
  #pragma unroll
  for (int r=0;r<4;r++){
    float att = sigmoidf_(dotr[r]+attb);
    int erow = mb + quad*4 + r;
    int dstN = s_dst[erow];
    #pragma unroll
    for (int nt=0;nt<8;nt++){
      float v = mval[nt][r]*att;
      mval[nt][r] = v;
      if constexpr (TIERA){
        s_hid[erow][nt*16+l15] = f2bf(v);
        atomicAdd(msgf + dstN*128 + nt*16 + l15, v);
      } else {
        s_m[erow][nt*16+l15] = f2bf(v);
      }
    }
    if constexpr (!TIERA){
      #pragma unroll
      for (int nt=0;nt<8;nt++){
        float part = __shfl_xor(mval[nt][r], 1);
        if ((l15 & 1) == 0){
          atomic_add_bf16pair((u32*)(msgb + dstN*128 + nt*16 + l15), mval[nt][r], part);
        }
      }
    }
  }
  // ---- GEMM2: ch_pre = m @ Wx1 (own rows)
  f32x4 acc2[8];
  #pragma unroll
  for (int nt=0;nt<8;nt++) acc2[nt]=(f32x4){0.f,0.f,0.f,0.f};
  #pragma unroll
  for (int ks=0;ks<4;ks++){
    short8 af = TIERA ? *(const short8*)&s_hid[mb+l15][ks*32+quad*8]
                      : *(const short8*)&s_m[mb+l15][ks*32+quad*8];
    #pragma unroll
    for (int nt=0;nt<8;nt++){
      short8 bfr = *(const short8*)(Wx1T + (nt*16+l15)*128 + ks*32+quad*8);
      acc2[nt] = __builtin_amdgcn_mfma_f32_16x16x32_bf16(af, bfr, acc2[nt], 0,0,0);
    }
  }
  // ---- epilogue: coord weight + fp32 atomics
  float bx1v[8], wx2v[8];
  #pragma unroll
  for (int nt=0;nt<8;nt++){ bx1v[nt]=IO<FP32>::ld(Wx1b, nt*16+l15); wx2v[nt]=IO<FP32>::ld(Wx2, nt*16+l15); }
  float bx2f = IO<FP32>::ld(Wx2b, 0);
  float dc[4];
  #pragma unroll
  for (int r=0;r<4;r++){
    float s=0.f;
    #pragma unroll
    for (int nt=0;nt<8;nt++){
      float u = acc2[nt][r] + bx1v[nt];
      u = u*sigmoidf_(u);
      s += u*wx2v[nt];
    }
    dc[r]=s;
  }
  #pragma unroll
  for (int off=1;off<16;off<<=1){
    #pragma unroll
    for (int r=0;r<4;r++) dc[r] += __shfl_xor(dc[r], off);
  }
  #pragma unroll
  for (int r=0;r<4;r++){
    float cw = tanhf(dc[r]+bx2f);
    if (l15==0){
      int erow = mb + quad*4 + r;
      int dstN = s_dst[erow];
      atomicAdd(&cagg[dstN*4+0], s_dif[erow][0]*cw);
      atomicAdd(&cagg[dstN*4+1], s_dif[erow][1]*cw);
      atomicAdd(&cagg[dstN*4+2], s_dif[erow][2]*cw);
      atomicAdd(&cagg[dstN*4+3], 1.0f);
    }
  }
}

// ---------------- node update ----------------
template<int FP32, int MSGF>
__global__ __launch_bounds__(256) void k_node(
    const int* __restrict__ flag,
    const void* __restrict__ h, const void* __restrict__ x,
    const float* __restrict__ msgf, const u16* __restrict__ msgb,
    const float* __restrict__ cagg,
    const u16* __restrict__ Wh1T, const void* __restrict__ Wh1b,
    const u16* __restrict__ Wh2T, const void* __restrict__ Wh2b,
    void* __restrict__ out)
{
  if (flag[0] != FP32) return;
  __shared__ __align__(16) u16 s_a[64][264];
  __shared__ __align__(16) u16 s_u[64][136];
  int tid = threadIdx.x; int nbase = blockIdx.x*64;
  {
    u32* p1 = (u32*)&s_a[0][0];
    for (int i = tid; i < 8448; i += 256) p1[i] = 0u;
  }
  __syncthreads();
  {
    int r = tid>>2, p = tid&3; int node = nbase + r;
    if (node < NN){
      #pragma unroll
      for (int c=0;c<8;c++){
        int col = p*64 + c*8;
        if (col < 128){
          float f[8]; IO<FP32>::ld8(h, node*128 + col, f);
          *(uint4*)&s_a[r][col] = pack8(f);
        } else if (MSGF){
          const float* mp = msgf + node*128 + (col-128);
          float f[8];
          *(f32x4*)&f[0] = *(const f32x4*)mp;
          *(f32x4*)&f[4] = *(const f32x4*)(mp+4);
          *(uint4*)&s_a[r][col] = pack8(f);
        } else {
          *(uint4*)&s_a[r][col] = *(const uint4*)(msgb + node*128 + (col-128));
        }
      }
    }
  }
  __syncthreads();
  int lane=tid&63, wid=tid>>6, quad=lane>>4, l15=lane&15, mb=wid*16;
  f32x4 acc[8];
  #pragma unroll
  for (int nt=0;nt<8;nt++) acc[nt]=(f32x4){0.f,0.f,0.f,0.f};
  #pragma unroll
  for (int ks=0;ks<8;ks++){
    short8 af = *(const short8*)&s_a[mb+l15][ks*32+quad*8];
    #pragma unroll
    for (int nt=0;nt<8;nt++){
      short8 bfr = *(const short8*)(Wh1T + (nt*16+l15)*256 + ks*32+quad*8);
      acc[nt] = __builtin_amdgcn_mfma_f32_16x16x32_bf16(af, bfr, acc[nt], 0,0,0);
    }
  }
  #pragma unroll
  for (int r=0;r<4;r++){
    int row = mb + quad*4 + r;
    #pragma unroll
    for (int nt=0;nt<8;nt++){
      int col = nt*16+l15;
      float u = acc[nt][r] + IO<FP32>::ld(Wh1b, col);
      u = u*sigmoidf_(u);
      s_u[row][col] = f2bf(u);
    }
  }
  f32x4 acc2[8];
  #pragma unroll
  for (int nt=0;nt<8;nt++) acc2[nt]=(f32x4){0.f,0.f,0.f,0.f};
  #pragma unroll
  for (int ks=0;ks<4;ks++){
    short8 af = *(const short8*)&s_u[mb+l15][ks*32+quad*8];
    #pragma unroll
    for (int nt=0;nt<8;nt++){
      short8 bfr = *(const short8*)(Wh2T + (nt*16+l15)*128 + ks*32+quad*8);
      acc2[nt] = __builtin_amdgcn_mfma_f32_16x16x32_bf16(af, bfr, acc2[nt], 0,0,0);
    }
  }
  #pragma unroll
  for (int r=0;r<4;r++){
    int node = nbase + mb + quad*4 + r;
    if (node < NN){
      #pragma unroll
      for (int nt=0;nt<8;nt++){
        int col = nt*16+l15;
        float v = IO<FP32>::ld(h, node*128+col) + acc2[nt][r] + IO<FP32>::ld(Wh2b, col);
        IO<FP32>::st(out, node*128+col, v);
      }
    }
  }
  if (tid < 64){
    int node = nbase + tid;
    if (node < NN){
      float inv = 1.0f/(cagg[node*4+3] + 1.0f);
      #pragma unroll
      for (int c=0;c<3;c++){
        float v = IO<FP32>::ld(x, node*3+c) + cagg[node*4+c]*inv;
        IO<FP32>::st(out, NN*128 + node*3 + c, v);
      }
    }
  }
}

extern "C" void kernel_launch(void* const* d_in, const int* in_sizes, int n_in,
                              void* d_out, int out_size, void* d_ws, size_t ws_size,
                              hipStream_t stream) {
  const void* h     = d_in[0];
  const void* x     = d_in[1];
  const void* ea    = d_in[2];
  const void* temb  = d_in[3];
  const void* We1   = d_in[4];
  const void* We1b  = d_in[5];
  const void* We2   = d_in[6];
  const void* We2b  = d_in[7];
  const void* Watt  = d_in[8];
  const void* Wattb = d_in[9];
  const void* Wx1   = d_in[10];
  const void* Wx1b  = d_in[11];
  const void* Wx2   = d_in[12];
  const void* Wx2b  = d_in[13];
  const void* Wh1   = d_in[14];
  const void* Wh1b  = d_in[15];
  const void* Wh2   = d_in[16];
  const void* Wh2b  = d_in[17];
  const int* eidx   = (const int*)d_in[18];
  char* ws = (char*)d_ws;

  u16* WprojT = (u16*)(ws + 0);          //  98,304
  u16* We2T   = (u16*)(ws + 98304);      //  32,768
  u16* Wx1T   = (u16*)(ws + 131072);     //  32,768
  u16* Wh1T   = (u16*)(ws + 163840);     //  65,536
  u16* Wh2T   = (u16*)(ws + 229376);     //  32,768  -> 262,144
  u16* Wrk9T  = (u16*)(ws + 262144);     //   8,192  -> 270,336
  float* cagg = (float*)(ws + 270336);   // 800,000  -> 1,070,336
  int* flag   = (int*)(ws + 1070336);    //     256  -> 1,070,592
  bool tierA = (ws_size >= (size_t)39470592);
  float* msgf = (float*)(ws + 1070592);
  u16*   msgb = (u16*)(ws + 1070592);
  u16*   P2   = (u16*)(ws + 26670592);   // tierA only
  u16*   P13  = (u16*)d_out;

  hipMemsetAsync(ws + 270336, 0, tierA ? 26400256 : 13600256, stream);
  k_probe<<<1, 64, 0, stream>>>((const u16*)h, flag);
  k_prep<0><<<528, 256, 0, stream>>>(flag, We1, We2, Wx1, Wh1, Wh2, WprojT, We2T, Wx1T, Wh1T, Wh2T, Wrk9T);
  k_prep<1><<<528, 256, 0, stream>>>(flag, We1, We2, Wx1, Wh1, Wh2, WprojT, We2T, Wx1T, Wh1T, Wh2T, Wrk9T);
  if (tierA){
    k_proj<0,1><<<(NN+63)/64, 256, 0, stream>>>(flag, h, temb, WprojT, We1b, P13, P2);
    k_proj<1,1><<<(NN+63)/64, 256, 0, stream>>>(flag, h, temb, WprojT, We1b, P13, P2);
    k_edge<0,1><<<EE/64, 256, 0, stream>>>(flag, x, ea, We1, h, We2b, Watt, Wattb, Wx1b, Wx2, Wx2b,
                                           eidx, P13, P2, WprojT, Wrk9T, We2T, Wx1T, msgf, msgb, cagg);
    k_edge<1,1><<<EE/64, 256, 0, stream>>>(flag, x, ea, We1, h, We2b, Watt, Wattb, Wx1b, Wx2, Wx2b,
                                           eidx, P13, P2, WprojT, Wrk9T, We2T, Wx1T, msgf, msgb, cagg);
    k_node<0,1><<<(NN+63)/64, 256, 0, stream>>>(flag, h, x, msgf, msgb, cagg, Wh1T, Wh1b, Wh2T, Wh2b, d_out);
    k_node<1,1><<<(NN+63)/64, 256, 0, stream>>>(flag, h, x, msgf, msgb, cagg, Wh1T, Wh1b, Wh2T, Wh2b, d_out);
  } else {
    k_proj<0,0><<<(NN+63)/64, 256, 0, stream>>>(flag, h, temb, WprojT, We1b, P13, P2);
    k_proj<1,0><<<(NN+63)/64, 256, 0, stream>>>(flag, h, temb, WprojT, We1b, P13, P2);
    k_edge<0,0><<<EE/64, 256, 0, stream>>>(flag, x, ea, We1, h, We2b, Watt, Wattb, Wx1b, Wx2, Wx2b,
                                           eidx, P13, P2, WprojT, Wrk9T, We2T, Wx1T, msgf, msgb, cagg);
    k_edge<1,0><<<EE/64, 256, 0, stream>>>(flag, x, ea, We1, h, We2b, Watt, Wattb, Wx1b, Wx2, Wx2b,
                                           eidx, P13, P2, WprojT, Wrk9T, We2T, Wx1T, msgf, msgb, cagg);
    k_node<0,0><<<(NN+63)/64, 256, 0, stream>>>(flag, h, x, msgf, msgb, cagg, Wh1T, Wh1b, Wh2T, Wh2b, d_out);
    k_node<1,0><<<(NN+63)/64, 256, 0, stream>>>(flag, h, x, msgf, msgb, cagg, Wh1T, Wh1b, Wh2T, Wh2b, d_out);
  }
}